// Round 4
// baseline (102671.960 us; speedup 1.0000x reference)
//
#include <hip/hip_runtime.h>
#include <math.h>

// ---------------------------------------------------------------------------
// PointerNet rollout on MI355X. fp32 throughout (argmax-exactness required).
// Scratch in __device__ globals (.bss). PRNG: JAX threefry2x32 partitionable.
// Round-4 structure: decoder = 2 kernels/step (lstm + fused attn).
// All dot-product fma chains identical to the round-3 PASSING kernel.
// ---------------------------------------------------------------------------

#define Bz 256
#define Sz 256
#define Ez 128
#define Hz 512
#define NEGV -1e9f
#define BH (Bz*Hz)

__device__ float g_encout[Bz*Sz*Hz];
__device__ float g_glref[Bz*Sz*Hz];
__device__ float g_ptref[Bz*Sz*Hz];
__device__ float g_h[2*BH];
__device__ float g_c[BH];
__device__ int g_ptrbuf[Bz];
__device__ unsigned g_keys[2*Sz];
__device__ unsigned char g_mask[Bz*Sz];

__device__ __forceinline__ unsigned rotl32(unsigned v, int d){ return (v<<d)|(v>>(32-d)); }

__device__ __forceinline__ void tf2x32(unsigned k0, unsigned k1, unsigned x0, unsigned x1,
                                       unsigned &o0, unsigned &o1){
  unsigned ks2 = k0 ^ k1 ^ 0x1BD11BDAu;
  x0 += k0; x1 += k1;
#define TFR(r) { x0 += x1; x1 = rotl32(x1,(r)); x1 ^= x0; }
  TFR(13) TFR(15) TFR(26) TFR(6)
  x0 += k1; x1 += ks2 + 1u;
  TFR(17) TFR(29) TFR(16) TFR(24)
  x0 += ks2; x1 += k0 + 2u;
  TFR(13) TFR(15) TFR(26) TFR(6)
  x0 += k0; x1 += k1 + 3u;
  TFR(17) TFR(29) TFR(16) TFR(24)
  x0 += k1; x1 += ks2 + 4u;
  TFR(13) TFR(15) TFR(26) TFR(6)
  x0 += ks2; x1 += k0 + 5u;
#undef TFR
  o0 = x0; o1 = x1;
}

__device__ __forceinline__ unsigned rng_bits(unsigned ka, unsigned kb, unsigned idx){
  unsigned o0,o1; tf2x32(ka,kb, 0u, idx, o0,o1);
  return o0 ^ o1;
}

// ---------------------------------------------------------------------------
__global__ __launch_bounds__(256) void init_kernel(){
  int i = blockIdx.x*256 + threadIdx.x;
  if (i < BH){ g_h[i] = 0.f; g_c[i] = 0.f; }
  if (i < Bz*Sz) g_mask[i] = 0;
  if (i < Sz){
    unsigned o0,o1; tf2x32(0u,1u, 0u, (unsigned)i, o0,o1);
    g_keys[2*i] = o0; g_keys[2*i+1] = o1;
  }
}

// ---------------------------------------------------------------------------
// LSTM step v2: A (x|h) staged to LDS as [b][k]; W read direct from global
// (row broadcast through L1, float4 per 4 k). Per-accumulator fma chain is
// k-ascending — bit-identical to the round-3 passing kernel.
// grid (8 btile, 32 jtile) x 256 thr; thread owns 2 b x (4 gates @ jglob).
// ---------------------------------------------------------------------------
__global__ __launch_bounds__(256) void lstm_step(
    const float* __restrict__ Wih,   // [2048][128]
    const float* __restrict__ Whh,   // [2048][512]
    const float* __restrict__ bias,  // [2048]
    const float* __restrict__ emb_table, // [Sz][Ez]
    const int*   __restrict__ inputs,    // [Bz][Sz]
    const float* __restrict__ dec_start, // [Ez]
    int t, int is_dec, int hsel)
{
  __shared__ float A_lds[32][36];   // [b][k], row stride 144B (16B-aligned)

  const float* h_in = g_h + (size_t)hsel*BH;
  float*       h_out = g_h + (size_t)(hsel^1)*BH;

  int tid = threadIdx.x;
  int bt = blockIdx.x, jt = blockIdx.y;
  int jj = tid & 15, bp = tid >> 4;
  int jglob = jt*16 + jj;

  float acc[2][4];
  {
    float b0v = bias[jglob];
    float b1v = bias[Hz + jglob];
    float b2v = bias[2*Hz + jglob];
    float b3v = bias[3*Hz + jglob];
    acc[0][0]=b0v; acc[0][1]=b1v; acc[0][2]=b2v; acc[0][3]=b3v;
    acc[1][0]=b0v; acc[1][1]=b1v; acc[1][2]=b2v; acc[1][3]=b3v;
  }

  int sb = tid >> 3;          // staging b 0..31
  int sk = (tid & 7) * 4;     // staging k offset
  int b0g = bt*32 + sb;

  for (int kc = 0; kc < 20; kc++){
    int k0 = kc*32;
    __syncthreads();
    {
      float4 av;
      if (k0 < Ez){
        const float* xrow;
        if (is_dec){
          xrow = (t == 0) ? dec_start
               : emb_table + (size_t)inputs[b0g*Sz + g_ptrbuf[b0g]] * Ez;
        } else {
          xrow = emb_table + (size_t)inputs[b0g*Sz + t] * Ez;
        }
        av = *(const float4*)(xrow + k0 + sk);
      } else {
        av = *(const float4*)(h_in + (size_t)b0g*Hz + (k0 - Ez) + sk);
      }
      *(float4*)&A_lds[sb][sk] = av;
    }
    __syncthreads();

    const float* wb; int wstride, koff;
    if (k0 < Ez){ wb = Wih; wstride = Ez; koff = k0; }
    else        { wb = Whh; wstride = Hz; koff = k0 - Ez; }
    const float* wp0 = wb + (size_t)jglob*wstride + koff;
    const float* wp1 = wb + (size_t)(Hz + jglob)*wstride + koff;
    const float* wp2 = wb + (size_t)(2*Hz + jglob)*wstride + koff;
    const float* wp3 = wb + (size_t)(3*Hz + jglob)*wstride + koff;

    #pragma unroll
    for (int k4 = 0; k4 < 8; k4++){
      float4 w0 = *(const float4*)(wp0 + k4*4);
      float4 w1 = *(const float4*)(wp1 + k4*4);
      float4 w2 = *(const float4*)(wp2 + k4*4);
      float4 w3 = *(const float4*)(wp3 + k4*4);
      float4 a0 = *(const float4*)&A_lds[bp*2][k4*4];
      float4 a1 = *(const float4*)&A_lds[bp*2+1][k4*4];
      acc[0][0]=fmaf(a0.x,w0.x,acc[0][0]); acc[0][1]=fmaf(a0.x,w1.x,acc[0][1]);
      acc[0][2]=fmaf(a0.x,w2.x,acc[0][2]); acc[0][3]=fmaf(a0.x,w3.x,acc[0][3]);
      acc[1][0]=fmaf(a1.x,w0.x,acc[1][0]); acc[1][1]=fmaf(a1.x,w1.x,acc[1][1]);
      acc[1][2]=fmaf(a1.x,w2.x,acc[1][2]); acc[1][3]=fmaf(a1.x,w3.x,acc[1][3]);
      acc[0][0]=fmaf(a0.y,w0.y,acc[0][0]); acc[0][1]=fmaf(a0.y,w1.y,acc[0][1]);
      acc[0][2]=fmaf(a0.y,w2.y,acc[0][2]); acc[0][3]=fmaf(a0.y,w3.y,acc[0][3]);
      acc[1][0]=fmaf(a1.y,w0.y,acc[1][0]); acc[1][1]=fmaf(a1.y,w1.y,acc[1][1]);
      acc[1][2]=fmaf(a1.y,w2.y,acc[1][2]); acc[1][3]=fmaf(a1.y,w3.y,acc[1][3]);
      acc[0][0]=fmaf(a0.z,w0.z,acc[0][0]); acc[0][1]=fmaf(a0.z,w1.z,acc[0][1]);
      acc[0][2]=fmaf(a0.z,w2.z,acc[0][2]); acc[0][3]=fmaf(a0.z,w3.z,acc[0][3]);
      acc[1][0]=fmaf(a1.z,w0.z,acc[1][0]); acc[1][1]=fmaf(a1.z,w1.z,acc[1][1]);
      acc[1][2]=fmaf(a1.z,w2.z,acc[1][2]); acc[1][3]=fmaf(a1.z,w3.z,acc[1][3]);
      acc[0][0]=fmaf(a0.w,w0.w,acc[0][0]); acc[0][1]=fmaf(a0.w,w1.w,acc[0][1]);
      acc[0][2]=fmaf(a0.w,w2.w,acc[0][2]); acc[0][3]=fmaf(a0.w,w3.w,acc[0][3]);
      acc[1][0]=fmaf(a1.w,w0.w,acc[1][0]); acc[1][1]=fmaf(a1.w,w1.w,acc[1][1]);
      acc[1][2]=fmaf(a1.w,w2.w,acc[1][2]); acc[1][3]=fmaf(a1.w,w3.w,acc[1][3]);
    }
  }

  int b0 = bt*32 + bp*2;
  #pragma unroll
  for (int r=0;r<2;r++){
    int b = b0 + r;
    float gi = acc[r][0], gf = acc[r][1], gg = acc[r][2], go = acc[r][3];
    float co = g_c[(size_t)b*Hz + jglob];
    float si = 1.f/(1.f + expf(-gi));
    float sf = 1.f/(1.f + expf(-gf));
    float so = 1.f/(1.f + expf(-go));
    float cn = sf*co + si*tanhf(gg);
    float hn = so*tanhf(cn);
    g_c[(size_t)b*Hz + jglob] = cn;
    h_out[(size_t)b*Hz + jglob] = hn;
    if (!is_dec) g_encout[((size_t)b*Sz + t)*Hz + jglob] = hn;
  }
}

// ---------------------------------------------------------------------------
// ref projections: C[65536][512] = enc_out @ W^T + b. 64x64 tile.
// ---------------------------------------------------------------------------
__global__ __launch_bounds__(256) void gemm_ref(
    const float* __restrict__ W, const float* __restrict__ bias, int dst_id)
{
  const float* A = g_encout;
  float*       C = (dst_id == 1) ? g_glref : g_ptref;
  __shared__ float As[32][68];
  __shared__ float Ws[32][68];
  int tid = threadIdx.x;
  int mt = blockIdx.x * 64, nt = blockIdx.y * 64;
  int tm = (tid & 15) * 4, tn = (tid >> 4) * 4;
  float acc[4][4] = {};
  int lr = tid >> 2;
  int lk = (tid & 3) * 8;

  for (int kc = 0; kc < 16; kc++){
    int k0 = kc*32;
    __syncthreads();
    {
      const float* ar = A + (size_t)(mt + lr)*Hz + k0 + lk;
      float4 a0 = *(const float4*)ar, a1 = *(const float4*)(ar+4);
      As[lk+0][lr]=a0.x; As[lk+1][lr]=a0.y; As[lk+2][lr]=a0.z; As[lk+3][lr]=a0.w;
      As[lk+4][lr]=a1.x; As[lk+5][lr]=a1.y; As[lk+6][lr]=a1.z; As[lk+7][lr]=a1.w;
      const float* wr = W + (size_t)(nt + lr)*Hz + k0 + lk;
      float4 w0 = *(const float4*)wr, w1 = *(const float4*)(wr+4);
      Ws[lk+0][lr]=w0.x; Ws[lk+1][lr]=w0.y; Ws[lk+2][lr]=w0.z; Ws[lk+3][lr]=w0.w;
      Ws[lk+4][lr]=w1.x; Ws[lk+5][lr]=w1.y; Ws[lk+6][lr]=w1.z; Ws[lk+7][lr]=w1.w;
    }
    __syncthreads();
    #pragma unroll
    for (int k=0;k<32;k++){
      float4 av = *(const float4*)&As[k][tm];
      float4 wv = *(const float4*)&Ws[k][tn];
      acc[0][0]=fmaf(av.x,wv.x,acc[0][0]); acc[0][1]=fmaf(av.x,wv.y,acc[0][1]);
      acc[0][2]=fmaf(av.x,wv.z,acc[0][2]); acc[0][3]=fmaf(av.x,wv.w,acc[0][3]);
      acc[1][0]=fmaf(av.y,wv.x,acc[1][0]); acc[1][1]=fmaf(av.y,wv.y,acc[1][1]);
      acc[1][2]=fmaf(av.y,wv.z,acc[1][2]); acc[1][3]=fmaf(av.y,wv.w,acc[1][3]);
      acc[2][0]=fmaf(av.z,wv.x,acc[2][0]); acc[2][1]=fmaf(av.z,wv.y,acc[2][1]);
      acc[2][2]=fmaf(av.z,wv.z,acc[2][2]); acc[2][3]=fmaf(av.z,wv.w,acc[2][3]);
      acc[3][0]=fmaf(av.w,wv.x,acc[3][0]); acc[3][1]=fmaf(av.w,wv.y,acc[3][1]);
      acc[3][2]=fmaf(av.w,wv.z,acc[3][2]); acc[3][3]=fmaf(av.w,wv.w,acc[3][3]);
    }
  }
  float b0v = bias[nt+tn+0], b1v = bias[nt+tn+1], b2v = bias[nt+tn+2], b3v = bias[nt+tn+3];
  #pragma unroll
  for (int i=0;i<4;i++){
    float4 o;
    o.x = acc[i][0] + b0v; o.y = acc[i][1] + b1v;
    o.z = acc[i][2] + b2v; o.w = acc[i][3] + b3v;
    *(float4*)(C + (size_t)(mt + tm + i)*Hz + nt + tn) = o;
  }
}

// ---------------------------------------------------------------------------
// Fused attention step (per-b block, 512 threads / 8 waves):
//   q2 = gl_Wq@h+bq  ->  glimpse online-softmax -> qg
//   qpt = pt_Wq@qg+bq -> pointer logits -> Gumbel sample -> mask/ptr update
// Glimpse: 16-row chunks, double-buffered register prefetch.
// ---------------------------------------------------------------------------
__global__ __launch_bounds__(512) void attn_step(
    const float* __restrict__ gl_Wq, const float* __restrict__ gl_bq,
    const float* __restrict__ gl_V,
    const float* __restrict__ pt_Wq, const float* __restrict__ pt_bq,
    const float* __restrict__ pt_V,
    int t, int hsel2, float* __restrict__ out)
{
  int b = blockIdx.x, tid = threadIdx.x;
  int wave = tid >> 6, lane64 = tid & 63;
  int g = tid >> 5, lane = tid & 31;

  __shared__ float hq[Hz];
  __shared__ float q2s[Hz];
  __shared__ float qgs[Hz];
  __shared__ float qps[Hz];
  __shared__ float vgl[Hz];
  __shared__ float vpt[Hz];
  __shared__ float tile[2][16][Hz];   // 64 KB
  __shared__ float lg16[16];
  __shared__ float slog[Sz];
  __shared__ float redy[8]; __shared__ int redi[8];
  __shared__ float redm[8]; __shared__ float redsum[8];

  hq[tid]  = g_h[(size_t)hsel2*BH + (size_t)b*Hz + tid];
  vgl[tid] = gl_V[tid];
  vpt[tid] = pt_V[tid];
  __syncthreads();

  const unsigned char* mrow = g_mask + b*Sz;

  // ---- q2 = gl_Wq @ h + gl_bq (wave w computes j = w*64..w*64+63)
  {
    float hv[8];
    #pragma unroll
    for (int i=0;i<8;i++) hv[i] = hq[lane64*8 + i];
    #pragma unroll 2
    for (int jj=0;jj<64;jj++){
      int j = wave*64 + jj;
      const float* wr = gl_Wq + (size_t)j*Hz + lane64*8;
      float4 w0 = *(const float4*)wr;
      float4 w1 = *(const float4*)(wr+4);
      float p = 0.f;
      p = fmaf(hv[0], w0.x, p); p = fmaf(hv[1], w0.y, p);
      p = fmaf(hv[2], w0.z, p); p = fmaf(hv[3], w0.w, p);
      p = fmaf(hv[4], w1.x, p); p = fmaf(hv[5], w1.y, p);
      p = fmaf(hv[6], w1.z, p); p = fmaf(hv[7], w1.w, p);
      #pragma unroll
      for (int off=32; off; off>>=1) p += __shfl_xor(p, off);
      if (lane64 == 0) q2s[j] = p + gl_bq[j];
    }
  }
  __syncthreads();

  // ---- glimpse: online softmax over unmasked rows, 16-row chunks, dbuf
  const float* glbase = g_glref + (size_t)b*Sz*Hz;
  float m = -INFINITY, l = 0.f, acc = 0.f;    // thread owns h = tid

  // stage chunk 0 (zero masked rows)
  {
    int s = g;
    if (mrow[s]){
      float4 z = {0.f,0.f,0.f,0.f};
      #pragma unroll
      for (int i=0;i<4;i++) *(float4*)&tile[0][g][(lane + i*32)*4] = z;
    } else {
      const float4* src = (const float4*)(glbase + (size_t)s*Hz);
      #pragma unroll
      for (int i=0;i<4;i++) *(float4*)&tile[0][g][(lane + i*32)*4] = src[lane + i*32];
    }
  }
  __syncthreads();

  int cur = 0;
  for (int c = 0; c < 16; c++){
    // prefetch chunk c+1 into regs
    float4 pf[4];
    bool have = (c + 1 < 16);
    {
      float4 z = {0.f,0.f,0.f,0.f};
      pf[0]=z; pf[1]=z; pf[2]=z; pf[3]=z;
      if (have){
        int nr = (c+1)*16 + g;
        if (!mrow[nr]){
          const float4* src = (const float4*)(glbase + (size_t)nr*Hz);
          #pragma unroll
          for (int i=0;i<4;i++) pf[i] = src[lane + i*32];
        }
      }
    }
    // dot for row s = c*16 + g
    {
      int s = c*16 + g;
      float lgv;
      if (mrow[s]) lgv = NEGV;
      else {
        float p = 0.f;
        #pragma unroll
        for (int mm=0;mm<16;mm++){
          int hh = lane + mm*32;
          p = fmaf(vgl[hh], tanhf(q2s[hh] + tile[cur][g][hh]), p);
        }
        #pragma unroll
        for (int off=16; off; off>>=1) p += __shfl_xor(p, off, 32);
        lgv = p;
      }
      if (lane == 0) lg16[g] = lgv;
    }
    __syncthreads();
    // online-softmax update (thread owns h = tid)
    {
      float lv[16];
      #pragma unroll
      for (int r=0;r<16;r++) lv[r] = lg16[r];
      float mx = lv[0];
      #pragma unroll
      for (int r=1;r<16;r++) mx = fmaxf(mx, lv[r]);
      float m_new = fmaxf(m, mx);
      float r_ = expf(m - m_new);
      float ps = 0.f, a = 0.f;
      #pragma unroll
      for (int r=0;r<16;r++){
        float pr = expf(lv[r] - m_new);
        ps += pr;
        a = fmaf(pr, tile[cur][r][tid], a);
      }
      acc = acc*r_ + a;
      l   = l*r_ + ps;
      m = m_new;
    }
    // write prefetched regs to other buffer (no hazard: different buffer)
    if (have){
      #pragma unroll
      for (int i=0;i<4;i++) *(float4*)&tile[cur^1][g][(lane + i*32)*4] = pf[i];
    }
    __syncthreads();
    cur ^= 1;
  }
  qgs[tid] = acc / l;
  __syncthreads();

  // ---- qpt = pt_Wq @ qg + pt_bq
  {
    float qv[8];
    #pragma unroll
    for (int i=0;i<8;i++) qv[i] = qgs[lane64*8 + i];
    #pragma unroll 2
    for (int jj=0;jj<64;jj++){
      int j = wave*64 + jj;
      const float* wr = pt_Wq + (size_t)j*Hz + lane64*8;
      float4 w0 = *(const float4*)wr;
      float4 w1 = *(const float4*)(wr+4);
      float p = 0.f;
      p = fmaf(qv[0], w0.x, p); p = fmaf(qv[1], w0.y, p);
      p = fmaf(qv[2], w0.z, p); p = fmaf(qv[3], w0.w, p);
      p = fmaf(qv[4], w1.x, p); p = fmaf(qv[5], w1.y, p);
      p = fmaf(qv[6], w1.z, p); p = fmaf(qv[7], w1.w, p);
      #pragma unroll
      for (int off=32; off; off>>=1) p += __shfl_xor(p, off);
      if (lane64 == 0) qps[j] = p + pt_bq[j];
    }
  }
  __syncthreads();

  // ---- pointer logits (direct global reads, 16 groups x 16 rows)
  const float* ptbase = g_ptref + (size_t)b*Sz*Hz;
  for (int c = 0; c < 16; c++){
    int s = c*16 + g;
    float lgv;
    if (mrow[s]) lgv = NEGV;
    else {
      const float* row = ptbase + (size_t)s*Hz;
      float p = 0.f;
      #pragma unroll
      for (int mm=0;mm<16;mm++){
        int hh = lane + mm*32;
        p = fmaf(vpt[hh], tanhf(qps[hh] + row[hh]), p);
      }
      #pragma unroll
      for (int off=16; off; off>>=1) p += __shfl_xor(p, off, 32);
      lgv = 10.f * tanhf(p);
    }
    if (lane == 0) slog[s] = lgv;
  }
  __syncthreads();

  // ---- Gumbel-max sample (threads 0..255 own s = tid)
  float lg = NEGV, y = -INFINITY;
  if (tid < Sz){
    lg = slog[tid];
    unsigned bits = rng_bits(g_keys[2*t], g_keys[2*t+1], (unsigned)(b*Sz + tid));
    float u = __uint_as_float((bits >> 9) | 0x3f800000u) - 1.f;
    float gum = -logf(-logf(u + 1e-10f) + 1e-10f);
    y = lg + gum;
  }
  float by = y; int bi = tid; float bm = lg;
  #pragma unroll
  for (int off=32; off; off>>=1){
    float oy = __shfl_xor(by, off);
    int   oi = __shfl_xor(bi, off);
    float om = __shfl_xor(bm, off);
    if (oy > by || (oy == by && oi < bi)){ by = oy; bi = oi; }
    bm = fmaxf(bm, om);
  }
  if (lane64 == 0){ redy[wave] = by; redi[wave] = bi; redm[wave] = bm; }
  __syncthreads();
  float fy = redy[0]; int fi = redi[0]; float fm = redm[0];
  #pragma unroll
  for (int w=1; w<8; w++){
    if (redy[w] > fy || (redy[w] == fy && redi[w] < fi)){ fy = redy[w]; fi = redi[w]; }
    fm = fmaxf(fm, redm[w]);
  }
  int ptr = fi;

  float pe = (tid < Sz) ? expf(lg - fm) : 0.f;
  #pragma unroll
  for (int off=32; off; off>>=1) pe += __shfl_xor(pe, off);
  if (lane64 == 0) redsum[wave] = pe;
  __syncthreads();
  if (tid == 0){
    float den = ((redsum[0]+redsum[1]) + (redsum[2]+redsum[3]))
              + ((redsum[4]+redsum[5]) + (redsum[6]+redsum[7]));
    float logp = slog[ptr] - fm - logf(den);
    out[(size_t)b*Sz + t] = (float)ptr;
    out[(size_t)Bz*Sz + (size_t)b*Sz + t] = logp;
    g_mask[b*Sz + ptr] = 1;
    g_ptrbuf[b] = ptr;
  }
}

// ---------------------------------------------------------------------------
extern "C" void kernel_launch(void* const* d_in, const int* in_sizes, int n_in,
                              void* d_out, int out_size, void* d_ws, size_t ws_size,
                              hipStream_t stream){
  (void)in_sizes; (void)n_in; (void)out_size; (void)d_ws; (void)ws_size;
  const float* embedding = (const float*)d_in[0];
  const float* enc_Wih = (const float*)d_in[1];
  const float* enc_Whh = (const float*)d_in[2];
  const float* enc_b   = (const float*)d_in[3];
  const float* dec_Wih = (const float*)d_in[4];
  const float* dec_Whh = (const float*)d_in[5];
  const float* dec_b   = (const float*)d_in[6];
  const float* pt_Wq   = (const float*)d_in[7];
  const float* pt_bq   = (const float*)d_in[8];
  const float* pt_Wref = (const float*)d_in[9];
  const float* pt_bref = (const float*)d_in[10];
  const float* pt_V    = (const float*)d_in[11];
  const float* gl_Wq   = (const float*)d_in[12];
  const float* gl_bq   = (const float*)d_in[13];
  const float* gl_Wref = (const float*)d_in[14];
  const float* gl_bref = (const float*)d_in[15];
  const float* gl_V    = (const float*)d_in[16];
  const float* dec_start = (const float*)d_in[17];
  const int*   inputs  = (const int*)d_in[18];
  float* out = (float*)d_out;

  init_kernel<<<512, 256, 0, stream>>>();

  // ---- encoder ----
  for (int t = 0; t < Sz; t++){
    lstm_step<<<dim3(8,32), 256, 0, stream>>>(enc_Wih, enc_Whh, enc_b,
        embedding, inputs, dec_start, t, 0, t & 1);
  }
  // ---- ref projections ----
  gemm_ref<<<dim3(1024,8), 256, 0, stream>>>(gl_Wref, gl_bref, 1);
  gemm_ref<<<dim3(1024,8), 256, 0, stream>>>(pt_Wref, pt_bref, 2);

  // ---- decoder: 2 kernels per step ----
  for (int t = 0; t < Sz; t++){
    lstm_step<<<dim3(8,32), 256, 0, stream>>>(dec_Wih, dec_Whh, dec_b,
        embedding, inputs, dec_start, t, 1, t & 1);
    attn_step<<<Bz, 512, 0, stream>>>(gl_Wq, gl_bq, gl_V,
        pt_Wq, pt_bq, pt_V, t, (t+1) & 1, out);
  }
}

// Round 5
// 56632.648 us; speedup vs baseline: 1.8129x; 1.8129x over previous
//
#include <hip/hip_runtime.h>
#include <math.h>

// ---------------------------------------------------------------------------
// PointerNet rollout on MI355X. fp32 throughout (argmax-exactness required).
// Scratch in __device__ globals (.bss). PRNG: JAX threefry2x32 partitionable.
// Round-5: attention restructured as sync-free streaming passes (latency fix);
// lstm_step reverted to the round-3 passing version.
// ---------------------------------------------------------------------------

#define Bz 256
#define Sz 256
#define Ez 128
#define Hz 512
#define NEGV -1e9f
#define BH (Bz*Hz)

__device__ float g_encout[Bz*Sz*Hz];
__device__ float g_glref[Bz*Sz*Hz];
__device__ float g_ptref[Bz*Sz*Hz];
__device__ float g_h[2*BH];
__device__ float g_c[BH];
__device__ int g_ptrbuf[Bz];
__device__ unsigned g_keys[2*Sz];
__device__ unsigned char g_mask[Bz*Sz];

__device__ __forceinline__ unsigned rotl32(unsigned v, int d){ return (v<<d)|(v>>(32-d)); }

__device__ __forceinline__ void tf2x32(unsigned k0, unsigned k1, unsigned x0, unsigned x1,
                                       unsigned &o0, unsigned &o1){
  unsigned ks2 = k0 ^ k1 ^ 0x1BD11BDAu;
  x0 += k0; x1 += k1;
#define TFR(r) { x0 += x1; x1 = rotl32(x1,(r)); x1 ^= x0; }
  TFR(13) TFR(15) TFR(26) TFR(6)
  x0 += k1; x1 += ks2 + 1u;
  TFR(17) TFR(29) TFR(16) TFR(24)
  x0 += ks2; x1 += k0 + 2u;
  TFR(13) TFR(15) TFR(26) TFR(6)
  x0 += k0; x1 += k1 + 3u;
  TFR(17) TFR(29) TFR(16) TFR(24)
  x0 += k1; x1 += ks2 + 4u;
  TFR(13) TFR(15) TFR(26) TFR(6)
  x0 += ks2; x1 += k0 + 5u;
#undef TFR
  o0 = x0; o1 = x1;
}

__device__ __forceinline__ unsigned rng_bits(unsigned ka, unsigned kb, unsigned idx){
  unsigned o0,o1; tf2x32(ka,kb, 0u, idx, o0,o1);
  return o0 ^ o1;
}

// ---------------------------------------------------------------------------
__global__ __launch_bounds__(256) void init_kernel(){
  int i = blockIdx.x*256 + threadIdx.x;
  if (i < BH){ g_h[i] = 0.f; g_c[i] = 0.f; }
  if (i < Bz*Sz) g_mask[i] = 0;
  if (i < Sz){
    unsigned o0,o1; tf2x32(0u,1u, 0u, (unsigned)i, o0,o1);
    g_keys[2*i] = o0; g_keys[2*i+1] = o1;
  }
}

// ---------------------------------------------------------------------------
// LSTM step (round-3 passing version, verbatim structure).
// Tile: 32 b x 16 j x 4 gates per WG. grid (8,32), 256 thr.
// ---------------------------------------------------------------------------
__global__ __launch_bounds__(256) void lstm_step(
    const float* __restrict__ Wih,   // [2048][128]
    const float* __restrict__ Whh,   // [2048][512]
    const float* __restrict__ bias,  // [2048]
    const float* __restrict__ emb_table, // [Sz][Ez]
    const int*   __restrict__ inputs,    // [Bz][Sz]
    const float* __restrict__ dec_start, // [Ez]
    int t, int is_dec, int hsel)
{
  __shared__ float A_lds[32][34];  // [k][b]
  __shared__ float W_lds[32][66];  // [k][r], r = gate*16 + jj

  const float* h_in = g_h + (size_t)hsel*BH;
  float*       h_out = g_h + (size_t)(hsel^1)*BH;

  int tid = threadIdx.x;
  int btile = blockIdx.x;          // 0..7
  int jtile = blockIdx.y;          // 0..31
  int jj = tid & 15;
  int bp = tid >> 4;               // 0..15
  int jglob = jtile*16 + jj;

  float acc[2][4];
  {
    float b0v = bias[0*Hz + jglob];
    float b1v = bias[1*Hz + jglob];
    float b2v = bias[2*Hz + jglob];
    float b3v = bias[3*Hz + jglob];
    acc[0][0]=b0v; acc[0][1]=b1v; acc[0][2]=b2v; acc[0][3]=b3v;
    acc[1][0]=b0v; acc[1][1]=b1v; acc[1][2]=b2v; acc[1][3]=b3v;
  }

  int lb  = tid >> 3;          // 0..31  A-stage row (b)
  int lk4 = (tid & 7) * 4;     // A-stage k offset (float4)
  int lr  = tid >> 2;          // 0..63  W-stage row
  int lk8 = (tid & 3) * 8;     // W-stage k offset (8 floats)
  int wR  = (lr >> 4)*Hz + jtile*16 + (lr & 15);  // global weight row

  for (int kc = 0; kc < 20; kc++){
    int k0 = kc*32;
    __syncthreads();
    // stage A
    {
      int bglob = btile*32 + lb;
      float4 av;
      if (k0 < Ez){
        const float* xrow;
        if (is_dec){
          if (t == 0) xrow = dec_start;
          else        xrow = emb_table + (size_t)inputs[bglob*Sz + g_ptrbuf[bglob]] * Ez;
        } else {
          xrow = emb_table + (size_t)inputs[bglob*Sz + t] * Ez;
        }
        av = *(const float4*)(xrow + k0 + lk4);
      } else {
        av = *(const float4*)(h_in + (size_t)bglob*Hz + (k0 - Ez) + lk4);
      }
      A_lds[lk4+0][lb] = av.x; A_lds[lk4+1][lb] = av.y;
      A_lds[lk4+2][lb] = av.z; A_lds[lk4+3][lb] = av.w;
    }
    // stage W
    {
      const float* wrow = (k0 < Ez) ? (Wih + (size_t)wR*Ez + k0)
                                    : (Whh + (size_t)wR*Hz + (k0 - Ez));
      float4 w0 = *(const float4*)(wrow + lk8);
      float4 w1 = *(const float4*)(wrow + lk8 + 4);
      W_lds[lk8+0][lr]=w0.x; W_lds[lk8+1][lr]=w0.y; W_lds[lk8+2][lr]=w0.z; W_lds[lk8+3][lr]=w0.w;
      W_lds[lk8+4][lr]=w1.x; W_lds[lk8+5][lr]=w1.y; W_lds[lk8+6][lr]=w1.z; W_lds[lk8+7][lr]=w1.w;
    }
    __syncthreads();
    #pragma unroll
    for (int k=0;k<32;k++){
      float2 a = *(const float2*)&A_lds[k][bp*2];
      float w0 = W_lds[k][jj];
      float w1 = W_lds[k][16+jj];
      float w2 = W_lds[k][32+jj];
      float w3 = W_lds[k][48+jj];
      acc[0][0] = fmaf(a.x, w0, acc[0][0]);
      acc[0][1] = fmaf(a.x, w1, acc[0][1]);
      acc[0][2] = fmaf(a.x, w2, acc[0][2]);
      acc[0][3] = fmaf(a.x, w3, acc[0][3]);
      acc[1][0] = fmaf(a.y, w0, acc[1][0]);
      acc[1][1] = fmaf(a.y, w1, acc[1][1]);
      acc[1][2] = fmaf(a.y, w2, acc[1][2]);
      acc[1][3] = fmaf(a.y, w3, acc[1][3]);
    }
  }

  int b0 = btile*32 + bp*2;
  #pragma unroll
  for (int r=0;r<2;r++){
    int b = b0 + r;
    float gi = acc[r][0], gf = acc[r][1], gg = acc[r][2], go = acc[r][3];
    float co = g_c[(size_t)b*Hz + jglob];
    float si = 1.f/(1.f + expf(-gi));
    float sf = 1.f/(1.f + expf(-gf));
    float so = 1.f/(1.f + expf(-go));
    float cn = sf*co + si*tanhf(gg);
    float hn = so*tanhf(cn);
    g_c[(size_t)b*Hz + jglob] = cn;
    h_out[(size_t)b*Hz + jglob] = hn;
    if (!is_dec) g_encout[((size_t)b*Sz + t)*Hz + jglob] = hn;
  }
}

// ---------------------------------------------------------------------------
// ref projections: C[65536][512] = enc_out @ W^T + b. 64x64 tile.
// ---------------------------------------------------------------------------
__global__ __launch_bounds__(256) void gemm_ref(
    const float* __restrict__ W, const float* __restrict__ bias, int dst_id)
{
  const float* A = g_encout;
  float*       C = (dst_id == 1) ? g_glref : g_ptref;
  __shared__ float As[32][68];
  __shared__ float Ws[32][68];
  int tid = threadIdx.x;
  int mt = blockIdx.x * 64, nt = blockIdx.y * 64;
  int tm = (tid & 15) * 4, tn = (tid >> 4) * 4;
  float acc[4][4] = {};
  int lr = tid >> 2;
  int lk = (tid & 3) * 8;

  for (int kc = 0; kc < 16; kc++){
    int k0 = kc*32;
    __syncthreads();
    {
      const float* ar = A + (size_t)(mt + lr)*Hz + k0 + lk;
      float4 a0 = *(const float4*)ar, a1 = *(const float4*)(ar+4);
      As[lk+0][lr]=a0.x; As[lk+1][lr]=a0.y; As[lk+2][lr]=a0.z; As[lk+3][lr]=a0.w;
      As[lk+4][lr]=a1.x; As[lk+5][lr]=a1.y; As[lk+6][lr]=a1.z; As[lk+7][lr]=a1.w;
      const float* wr = W + (size_t)(nt + lr)*Hz + k0 + lk;
      float4 w0 = *(const float4*)wr, w1 = *(const float4*)(wr+4);
      Ws[lk+0][lr]=w0.x; Ws[lk+1][lr]=w0.y; Ws[lk+2][lr]=w0.z; Ws[lk+3][lr]=w0.w;
      Ws[lk+4][lr]=w1.x; Ws[lk+5][lr]=w1.y; Ws[lk+6][lr]=w1.z; Ws[lk+7][lr]=w1.w;
    }
    __syncthreads();
    #pragma unroll
    for (int k=0;k<32;k++){
      float4 av = *(const float4*)&As[k][tm];
      float4 wv = *(const float4*)&Ws[k][tn];
      acc[0][0]=fmaf(av.x,wv.x,acc[0][0]); acc[0][1]=fmaf(av.x,wv.y,acc[0][1]);
      acc[0][2]=fmaf(av.x,wv.z,acc[0][2]); acc[0][3]=fmaf(av.x,wv.w,acc[0][3]);
      acc[1][0]=fmaf(av.y,wv.x,acc[1][0]); acc[1][1]=fmaf(av.y,wv.y,acc[1][1]);
      acc[1][2]=fmaf(av.y,wv.z,acc[1][2]); acc[1][3]=fmaf(av.y,wv.w,acc[1][3]);
      acc[2][0]=fmaf(av.z,wv.x,acc[2][0]); acc[2][1]=fmaf(av.z,wv.y,acc[2][1]);
      acc[2][2]=fmaf(av.z,wv.z,acc[2][2]); acc[2][3]=fmaf(av.z,wv.w,acc[2][3]);
      acc[3][0]=fmaf(av.w,wv.x,acc[3][0]); acc[3][1]=fmaf(av.w,wv.y,acc[3][1]);
      acc[3][2]=fmaf(av.w,wv.z,acc[3][2]); acc[3][3]=fmaf(av.w,wv.w,acc[3][3]);
    }
  }
  float b0v = bias[nt+tn+0], b1v = bias[nt+tn+1], b2v = bias[nt+tn+2], b3v = bias[nt+tn+3];
  #pragma unroll
  for (int i=0;i<4;i++){
    float4 o;
    o.x = acc[i][0] + b0v; o.y = acc[i][1] + b1v;
    o.z = acc[i][2] + b2v; o.w = acc[i][3] + b3v;
    *(float4*)(C + (size_t)(mt + tm + i)*Hz + nt + tn) = o;
  }
}

// ---------------------------------------------------------------------------
// Fused attention step, round-5 structure: sync-free streaming passes.
// Per-b block, 512 threads / 8 waves / 16 groups of 32 lanes.
//   q2 = gl_Wq@h+bq
//   glimpse pass1: group g streams rows [g*16, g*16+16) -> logits slog[]
//   block reduce: m_gl, l_gl
//   glimpse pass2: group g accumulates exp(slog-m)*row into regs; LDS merge
//   qpt = pt_Wq@qg+bq
//   pointer pass: streaming logits -> slog[]
//   Gumbel-max sample (verbatim from passing round-4 kernel)
// ---------------------------------------------------------------------------
__global__ __launch_bounds__(512) void attn_step(
    const float* __restrict__ gl_Wq, const float* __restrict__ gl_bq,
    const float* __restrict__ gl_V,
    const float* __restrict__ pt_Wq, const float* __restrict__ pt_bq,
    const float* __restrict__ pt_V,
    int t, int hsel2, float* __restrict__ out)
{
  int b = blockIdx.x, tid = threadIdx.x;
  int wave = tid >> 6, lane64 = tid & 63;
  int g = tid >> 5, lane = tid & 31;

  __shared__ __align__(16) float hq[Hz];
  __shared__ __align__(16) float q2s[Hz];
  __shared__ __align__(16) float qgs[Hz];
  __shared__ __align__(16) float qps[Hz];
  __shared__ __align__(16) float vgl[Hz];
  __shared__ __align__(16) float vpt[Hz];
  __shared__ __align__(16) float part[16][Hz];   // 32 KB
  __shared__ float slog[Sz];
  __shared__ float redy[8]; __shared__ int redi[8];
  __shared__ float redm[8]; __shared__ float redsum[8];

  hq[tid]  = g_h[(size_t)hsel2*BH + (size_t)b*Hz + tid];
  vgl[tid] = gl_V[tid];
  vpt[tid] = pt_V[tid];
  __syncthreads();

  const unsigned char* mrow = g_mask + b*Sz;

  // ---- q2 = gl_Wq @ h + gl_bq (wave w computes j = w*64..w*64+63)
  {
    float hv[8];
    #pragma unroll
    for (int i=0;i<8;i++) hv[i] = hq[lane64*8 + i];
    #pragma unroll 2
    for (int jj=0;jj<64;jj++){
      int j = wave*64 + jj;
      const float* wr = gl_Wq + (size_t)j*Hz + lane64*8;
      float4 w0 = *(const float4*)wr;
      float4 w1 = *(const float4*)(wr+4);
      float p = 0.f;
      p = fmaf(hv[0], w0.x, p); p = fmaf(hv[1], w0.y, p);
      p = fmaf(hv[2], w0.z, p); p = fmaf(hv[3], w0.w, p);
      p = fmaf(hv[4], w1.x, p); p = fmaf(hv[5], w1.y, p);
      p = fmaf(hv[6], w1.z, p); p = fmaf(hv[7], w1.w, p);
      #pragma unroll
      for (int off=32; off; off>>=1) p += __shfl_xor(p, off);
      if (lane64 == 0) q2s[j] = p + gl_bq[j];
    }
  }
  __syncthreads();

  // ---- glimpse pass 1: streaming logits (no barriers inside)
  const float* glbase = g_glref + (size_t)b*Sz*Hz;
  for (int r = 0; r < 16; r++){
    int s = g*16 + r;
    float lgv;
    if (mrow[s]) lgv = NEGV;
    else {
      const float4* row4 = (const float4*)(glbase + (size_t)s*Hz);
      float p = 0.f;
      #pragma unroll
      for (int i=0;i<4;i++){
        int idx = lane + i*32;
        float4 x  = row4[idx];
        float4 q  = *(const float4*)&q2s[idx*4];
        float4 vv = *(const float4*)&vgl[idx*4];
        p = fmaf(vv.x, tanhf(q.x + x.x), p);
        p = fmaf(vv.y, tanhf(q.y + x.y), p);
        p = fmaf(vv.z, tanhf(q.z + x.z), p);
        p = fmaf(vv.w, tanhf(q.w + x.w), p);
      }
      #pragma unroll
      for (int off=16; off; off>>=1) p += __shfl_xor(p, off, 32);
      lgv = p;
    }
    if (lane == 0) slog[s] = lgv;
  }
  __syncthreads();

  // ---- block reduce: m_gl, l_gl
  float m_gl, l_gl;
  {
    float v = (tid < Sz) ? slog[tid] : NEGV;
    float mv = v;
    #pragma unroll
    for (int off=32; off; off>>=1) mv = fmaxf(mv, __shfl_xor(mv, off));
    if (lane64 == 0) redm[wave] = mv;
    __syncthreads();
    m_gl = redm[0];
    #pragma unroll
    for (int w=1; w<8; w++) m_gl = fmaxf(m_gl, redm[w]);
    float pe = (tid < Sz) ? expf(v - m_gl) : 0.f;
    #pragma unroll
    for (int off=32; off; off>>=1) pe += __shfl_xor(pe, off);
    if (lane64 == 0) redsum[wave] = pe;
    __syncthreads();
    l_gl = ((redsum[0]+redsum[1]) + (redsum[2]+redsum[3]))
         + ((redsum[4]+redsum[5]) + (redsum[6]+redsum[7]));
  }

  // ---- glimpse pass 2: weighted accumulate in registers, merge via LDS
  {
    float4 racc[4];
    float4 z = {0.f,0.f,0.f,0.f};
    racc[0]=z; racc[1]=z; racc[2]=z; racc[3]=z;
    for (int r = 0; r < 16; r++){
      int s = g*16 + r;
      if (!mrow[s]){
        float pr = expf(slog[s] - m_gl);
        const float4* row4 = (const float4*)(glbase + (size_t)s*Hz);
        #pragma unroll
        for (int i=0;i<4;i++){
          float4 x = row4[lane + i*32];
          racc[i].x = fmaf(pr, x.x, racc[i].x);
          racc[i].y = fmaf(pr, x.y, racc[i].y);
          racc[i].z = fmaf(pr, x.z, racc[i].z);
          racc[i].w = fmaf(pr, x.w, racc[i].w);
        }
      }
    }
    #pragma unroll
    for (int i=0;i<4;i++) *(float4*)&part[g][(lane + i*32)*4] = racc[i];
  }
  __syncthreads();
  {
    float a = 0.f;
    #pragma unroll
    for (int gg=0; gg<16; gg++) a += part[gg][tid];
    qgs[tid] = a / l_gl;
  }
  __syncthreads();

  // ---- qpt = pt_Wq @ qg + pt_bq
  {
    float qv[8];
    #pragma unroll
    for (int i=0;i<8;i++) qv[i] = qgs[lane64*8 + i];
    #pragma unroll 2
    for (int jj=0;jj<64;jj++){
      int j = wave*64 + jj;
      const float* wr = pt_Wq + (size_t)j*Hz + lane64*8;
      float4 w0 = *(const float4*)wr;
      float4 w1 = *(const float4*)(wr+4);
      float p = 0.f;
      p = fmaf(qv[0], w0.x, p); p = fmaf(qv[1], w0.y, p);
      p = fmaf(qv[2], w0.z, p); p = fmaf(qv[3], w0.w, p);
      p = fmaf(qv[4], w1.x, p); p = fmaf(qv[5], w1.y, p);
      p = fmaf(qv[6], w1.z, p); p = fmaf(qv[7], w1.w, p);
      #pragma unroll
      for (int off=32; off; off>>=1) p += __shfl_xor(p, off);
      if (lane64 == 0) qps[j] = p + pt_bq[j];
    }
  }
  __syncthreads();

  // ---- pointer pass: streaming logits (no barriers inside)
  const float* ptbase = g_ptref + (size_t)b*Sz*Hz;
  for (int r = 0; r < 16; r++){
    int s = g*16 + r;
    float lgv;
    if (mrow[s]) lgv = NEGV;
    else {
      const float4* row4 = (const float4*)(ptbase + (size_t)s*Hz);
      float p = 0.f;
      #pragma unroll
      for (int i=0;i<4;i++){
        int idx = lane + i*32;
        float4 x  = row4[idx];
        float4 q  = *(const float4*)&qps[idx*4];
        float4 vv = *(const float4*)&vpt[idx*4];
        p = fmaf(vv.x, tanhf(q.x + x.x), p);
        p = fmaf(vv.y, tanhf(q.y + x.y), p);
        p = fmaf(vv.z, tanhf(q.z + x.z), p);
        p = fmaf(vv.w, tanhf(q.w + x.w), p);
      }
      #pragma unroll
      for (int off=16; off; off>>=1) p += __shfl_xor(p, off, 32);
      lgv = 10.f * tanhf(p);
    }
    if (lane == 0) slog[s] = lgv;
  }
  __syncthreads();

  // ---- Gumbel-max sample (threads 0..255 own s = tid) — r4 verbatim
  float lg = NEGV, y = -INFINITY;
  if (tid < Sz){
    lg = slog[tid];
    unsigned bits = rng_bits(g_keys[2*t], g_keys[2*t+1], (unsigned)(b*Sz + tid));
    float u = __uint_as_float((bits >> 9) | 0x3f800000u) - 1.f;
    float gum = -logf(-logf(u + 1e-10f) + 1e-10f);
    y = lg + gum;
  }
  float by = y; int bi = tid; float bm = lg;
  #pragma unroll
  for (int off=32; off; off>>=1){
    float oy = __shfl_xor(by, off);
    int   oi = __shfl_xor(bi, off);
    float om = __shfl_xor(bm, off);
    if (oy > by || (oy == by && oi < bi)){ by = oy; bi = oi; }
    bm = fmaxf(bm, om);
  }
  if (lane64 == 0){ redy[wave] = by; redi[wave] = bi; redm[wave] = bm; }
  __syncthreads();
  float fy = redy[0]; int fi = redi[0]; float fm = redm[0];
  #pragma unroll
  for (int w=1; w<8; w++){
    if (redy[w] > fy || (redy[w] == fy && redi[w] < fi)){ fy = redy[w]; fi = redi[w]; }
    fm = fmaxf(fm, redm[w]);
  }
  int ptr = fi;

  float pe = (tid < Sz) ? expf(lg - fm) : 0.f;
  #pragma unroll
  for (int off=32; off; off>>=1) pe += __shfl_xor(pe, off);
  if (lane64 == 0) redsum[wave] = pe;
  __syncthreads();
  if (tid == 0){
    float den = ((redsum[0]+redsum[1]) + (redsum[2]+redsum[3]))
              + ((redsum[4]+redsum[5]) + (redsum[6]+redsum[7]));
    float logp = slog[ptr] - fm - logf(den);
    out[(size_t)b*Sz + t] = (float)ptr;
    out[(size_t)Bz*Sz + (size_t)b*Sz + t] = logp;
    g_mask[b*Sz + ptr] = 1;
    g_ptrbuf[b] = ptr;
  }
}

// ---------------------------------------------------------------------------
extern "C" void kernel_launch(void* const* d_in, const int* in_sizes, int n_in,
                              void* d_out, int out_size, void* d_ws, size_t ws_size,
                              hipStream_t stream){
  (void)in_sizes; (void)n_in; (void)out_size; (void)d_ws; (void)ws_size;
  const float* embedding = (const float*)d_in[0];
  const float* enc_Wih = (const float*)d_in[1];
  const float* enc_Whh = (const float*)d_in[2];
  const float* enc_b   = (const float*)d_in[3];
  const float* dec_Wih = (const float*)d_in[4];
  const float* dec_Whh = (const float*)d_in[5];
  const float* dec_b   = (const float*)d_in[6];
  const float* pt_Wq   = (const float*)d_in[7];
  const float* pt_bq   = (const float*)d_in[8];
  const float* pt_Wref = (const float*)d_in[9];
  const float* pt_bref = (const float*)d_in[10];
  const float* pt_V    = (const float*)d_in[11];
  const float* gl_Wq   = (const float*)d_in[12];
  const float* gl_bq   = (const float*)d_in[13];
  const float* gl_Wref = (const float*)d_in[14];
  const float* gl_bref = (const float*)d_in[15];
  const float* gl_V    = (const float*)d_in[16];
  const float* dec_start = (const float*)d_in[17];
  const int*   inputs  = (const int*)d_in[18];
  float* out = (float*)d_out;

  init_kernel<<<512, 256, 0, stream>>>();

  // ---- encoder ----
  for (int t = 0; t < Sz; t++){
    lstm_step<<<dim3(8,32), 256, 0, stream>>>(enc_Wih, enc_Whh, enc_b,
        embedding, inputs, dec_start, t, 0, t & 1);
  }
  // ---- ref projections ----
  gemm_ref<<<dim3(1024,8), 256, 0, stream>>>(gl_Wref, gl_bref, 1);
  gemm_ref<<<dim3(1024,8), 256, 0, stream>>>(pt_Wref, pt_bref, 2);

  // ---- decoder: 2 kernels per step ----
  for (int t = 0; t < Sz; t++){
    lstm_step<<<dim3(8,32), 256, 0, stream>>>(dec_Wih, dec_Whh, dec_b,
        embedding, inputs, dec_start, t, 1, t & 1);
    attn_step<<<Bz, 512, 0, stream>>>(gl_Wq, gl_bq, gl_V,
        pt_Wq, pt_bq, pt_V, t, (t+1) & 1, out);
  }
}

// Round 6
// 43446.521 us; speedup vs baseline: 2.3632x; 1.3035x over previous
//
#include <hip/hip_runtime.h>
#include <math.h>

// ---------------------------------------------------------------------------
// PointerNet rollout on MI355X. fp32 throughout (argmax-exactness required).
// Round-6: (1) attn_step = 1024 thr, online-softmax glimpse (single gl_ref
// read, masked rows never loaded); (2) lstm_step = 4b x 4gate thread tile,
// b128 LDS reads, VALU-bound. Logit fma chains bit-identical to round 5.
// ---------------------------------------------------------------------------

#define Bz 256
#define Sz 256
#define Ez 128
#define Hz 512
#define NEGV -1e9f
#define BH (Bz*Hz)

__device__ float g_encout[Bz*Sz*Hz];
__device__ float g_glref[Bz*Sz*Hz];
__device__ float g_ptref[Bz*Sz*Hz];
__device__ float g_h[2*BH];
__device__ float g_c[BH];
__device__ int g_ptrbuf[Bz];
__device__ unsigned g_keys[2*Sz];
__device__ unsigned char g_mask[Bz*Sz];

__device__ __forceinline__ unsigned rotl32(unsigned v, int d){ return (v<<d)|(v>>(32-d)); }

__device__ __forceinline__ void tf2x32(unsigned k0, unsigned k1, unsigned x0, unsigned x1,
                                       unsigned &o0, unsigned &o1){
  unsigned ks2 = k0 ^ k1 ^ 0x1BD11BDAu;
  x0 += k0; x1 += k1;
#define TFR(r) { x0 += x1; x1 = rotl32(x1,(r)); x1 ^= x0; }
  TFR(13) TFR(15) TFR(26) TFR(6)
  x0 += k1; x1 += ks2 + 1u;
  TFR(17) TFR(29) TFR(16) TFR(24)
  x0 += ks2; x1 += k0 + 2u;
  TFR(13) TFR(15) TFR(26) TFR(6)
  x0 += k0; x1 += k1 + 3u;
  TFR(17) TFR(29) TFR(16) TFR(24)
  x0 += k1; x1 += ks2 + 4u;
  TFR(13) TFR(15) TFR(26) TFR(6)
  x0 += ks2; x1 += k0 + 5u;
#undef TFR
  o0 = x0; o1 = x1;
}

__device__ __forceinline__ unsigned rng_bits(unsigned ka, unsigned kb, unsigned idx){
  unsigned o0,o1; tf2x32(ka,kb, 0u, idx, o0,o1);
  return o0 ^ o1;
}

// ---------------------------------------------------------------------------
__global__ __launch_bounds__(256) void init_kernel(){
  int i = blockIdx.x*256 + threadIdx.x;
  if (i < BH){ g_h[i] = 0.f; g_c[i] = 0.f; }
  if (i < Bz*Sz) g_mask[i] = 0;
  if (i < Sz){
    unsigned o0,o1; tf2x32(0u,1u, 0u, (unsigned)i, o0,o1);
    g_keys[2*i] = o0; g_keys[2*i+1] = o1;
  }
}

// ---------------------------------------------------------------------------
// LSTM step v3: thread tile 4b x 4gates. Block 256 thr = 16 bp x 16 jj,
// covers 64 b x (16 j x 4 gates). grid (4,32) = 128 blocks.
// A and W staged to LDS as [row][k] (b128 reads, broadcast-friendly).
// Per-accumulator fma chain is k-ascending 0..639 (bit-identical h/c).
// ---------------------------------------------------------------------------
__global__ __launch_bounds__(256) void lstm_step(
    const float* __restrict__ Wih,   // [2048][128]
    const float* __restrict__ Whh,   // [2048][512]
    const float* __restrict__ bias,  // [2048]
    const float* __restrict__ emb_table, // [Sz][Ez]
    const int*   __restrict__ inputs,    // [Bz][Sz]
    const float* __restrict__ dec_start, // [Ez]
    int t, int is_dec, int hsel)
{
  __shared__ float A_lds[64][36];   // [b][k]
  __shared__ float W_lds[64][36];   // [row][k], row = gate*16 + jj

  const float* h_in = g_h + (size_t)hsel*BH;
  float*       h_out = g_h + (size_t)(hsel^1)*BH;

  int tid = threadIdx.x;
  int bt = blockIdx.x;     // 0..3 (64 b each)
  int jt = blockIdx.y;     // 0..31 (16 j each)
  int jj = tid & 15;
  int bp = tid >> 4;       // 0..15 (4 b each)
  int jglob = jt*16 + jj;
  int bq = bp*4;

  float acc[4][4];
  {
    float b0v = bias[jglob];
    float b1v = bias[Hz + jglob];
    float b2v = bias[2*Hz + jglob];
    float b3v = bias[3*Hz + jglob];
    #pragma unroll
    for (int r=0;r<4;r++){ acc[r][0]=b0v; acc[r][1]=b1v; acc[r][2]=b2v; acc[r][3]=b3v; }
  }

  int sr = tid >> 2;          // 0..63 staging row
  int sk = (tid & 3) * 8;     // k offset (2 float4)
  int bg = bt*64 + sr;        // global b for A staging
  int wrow_g = (sr >> 4)*Hz + jt*16 + (sr & 15);  // global W row for W staging

  for (int kc = 0; kc < 20; kc++){
    int k0 = kc*32;
    __syncthreads();
    // stage A
    {
      const float* src;
      if (k0 < Ez){
        const float* xrow;
        if (is_dec){
          xrow = (t == 0) ? dec_start
               : emb_table + (size_t)inputs[bg*Sz + g_ptrbuf[bg]] * Ez;
        } else {
          xrow = emb_table + (size_t)inputs[bg*Sz + t] * Ez;
        }
        src = xrow + k0 + sk;
      } else {
        src = h_in + (size_t)bg*Hz + (k0 - Ez) + sk;
      }
      float4 a0 = *(const float4*)src;
      float4 a1 = *(const float4*)(src + 4);
      *(float4*)&A_lds[sr][sk]     = a0;
      *(float4*)&A_lds[sr][sk + 4] = a1;
    }
    // stage W
    {
      const float* wr = (k0 < Ez) ? (Wih + (size_t)wrow_g*Ez + k0 + sk)
                                  : (Whh + (size_t)wrow_g*Hz + (k0 - Ez) + sk);
      float4 w0 = *(const float4*)wr;
      float4 w1 = *(const float4*)(wr + 4);
      *(float4*)&W_lds[sr][sk]     = w0;
      *(float4*)&W_lds[sr][sk + 4] = w1;
    }
    __syncthreads();
    #pragma unroll
    for (int k4 = 0; k4 < 8; k4++){
      float4 w0 = *(const float4*)&W_lds[jj      ][k4*4];
      float4 w1 = *(const float4*)&W_lds[16 + jj ][k4*4];
      float4 w2 = *(const float4*)&W_lds[32 + jj ][k4*4];
      float4 w3 = *(const float4*)&W_lds[48 + jj ][k4*4];
      float4 a0 = *(const float4*)&A_lds[bq + 0][k4*4];
      float4 a1 = *(const float4*)&A_lds[bq + 1][k4*4];
      float4 a2 = *(const float4*)&A_lds[bq + 2][k4*4];
      float4 a3 = *(const float4*)&A_lds[bq + 3][k4*4];
      // k ascending: components x,y,z,w
#define LSTEP(c) \
      acc[0][0]=fmaf(a0.c,w0.c,acc[0][0]); acc[0][1]=fmaf(a0.c,w1.c,acc[0][1]); \
      acc[0][2]=fmaf(a0.c,w2.c,acc[0][2]); acc[0][3]=fmaf(a0.c,w3.c,acc[0][3]); \
      acc[1][0]=fmaf(a1.c,w0.c,acc[1][0]); acc[1][1]=fmaf(a1.c,w1.c,acc[1][1]); \
      acc[1][2]=fmaf(a1.c,w2.c,acc[1][2]); acc[1][3]=fmaf(a1.c,w3.c,acc[1][3]); \
      acc[2][0]=fmaf(a2.c,w0.c,acc[2][0]); acc[2][1]=fmaf(a2.c,w1.c,acc[2][1]); \
      acc[2][2]=fmaf(a2.c,w2.c,acc[2][2]); acc[2][3]=fmaf(a2.c,w3.c,acc[2][3]); \
      acc[3][0]=fmaf(a3.c,w0.c,acc[3][0]); acc[3][1]=fmaf(a3.c,w1.c,acc[3][1]); \
      acc[3][2]=fmaf(a3.c,w2.c,acc[3][2]); acc[3][3]=fmaf(a3.c,w3.c,acc[3][3]);
      LSTEP(x) LSTEP(y) LSTEP(z) LSTEP(w)
#undef LSTEP
    }
  }

  #pragma unroll
  for (int r=0;r<4;r++){
    int b = bt*64 + bq + r;
    float gi = acc[r][0], gf = acc[r][1], gg = acc[r][2], go = acc[r][3];
    float co = g_c[(size_t)b*Hz + jglob];
    float si = 1.f/(1.f + expf(-gi));
    float sf = 1.f/(1.f + expf(-gf));
    float so = 1.f/(1.f + expf(-go));
    float cn = sf*co + si*tanhf(gg);
    float hn = so*tanhf(cn);
    g_c[(size_t)b*Hz + jglob] = cn;
    h_out[(size_t)b*Hz + jglob] = hn;
    if (!is_dec) g_encout[((size_t)b*Sz + t)*Hz + jglob] = hn;
  }
}

// ---------------------------------------------------------------------------
// ref projections: C[65536][512] = enc_out @ W^T + b. 64x64 tile.
// ---------------------------------------------------------------------------
__global__ __launch_bounds__(256) void gemm_ref(
    const float* __restrict__ W, const float* __restrict__ bias, int dst_id)
{
  const float* A = g_encout;
  float*       C = (dst_id == 1) ? g_glref : g_ptref;
  __shared__ float As[32][68];
  __shared__ float Ws[32][68];
  int tid = threadIdx.x;
  int mt = blockIdx.x * 64, nt = blockIdx.y * 64;
  int tm = (tid & 15) * 4, tn = (tid >> 4) * 4;
  float acc[4][4] = {};
  int lr = tid >> 2;
  int lk = (tid & 3) * 8;

  for (int kc = 0; kc < 16; kc++){
    int k0 = kc*32;
    __syncthreads();
    {
      const float* ar = A + (size_t)(mt + lr)*Hz + k0 + lk;
      float4 a0 = *(const float4*)ar, a1 = *(const float4*)(ar+4);
      As[lk+0][lr]=a0.x; As[lk+1][lr]=a0.y; As[lk+2][lr]=a0.z; As[lk+3][lr]=a0.w;
      As[lk+4][lr]=a1.x; As[lk+5][lr]=a1.y; As[lk+6][lr]=a1.z; As[lk+7][lr]=a1.w;
      const float* wr = W + (size_t)(nt + lr)*Hz + k0 + lk;
      float4 w0 = *(const float4*)wr, w1 = *(const float4*)(wr+4);
      Ws[lk+0][lr]=w0.x; Ws[lk+1][lr]=w0.y; Ws[lk+2][lr]=w0.z; Ws[lk+3][lr]=w0.w;
      Ws[lk+4][lr]=w1.x; Ws[lk+5][lr]=w1.y; Ws[lk+6][lr]=w1.z; Ws[lk+7][lr]=w1.w;
    }
    __syncthreads();
    #pragma unroll
    for (int k=0;k<32;k++){
      float4 av = *(const float4*)&As[k][tm];
      float4 wv = *(const float4*)&Ws[k][tn];
      acc[0][0]=fmaf(av.x,wv.x,acc[0][0]); acc[0][1]=fmaf(av.x,wv.y,acc[0][1]);
      acc[0][2]=fmaf(av.x,wv.z,acc[0][2]); acc[0][3]=fmaf(av.x,wv.w,acc[0][3]);
      acc[1][0]=fmaf(av.y,wv.x,acc[1][0]); acc[1][1]=fmaf(av.y,wv.y,acc[1][1]);
      acc[1][2]=fmaf(av.y,wv.z,acc[1][2]); acc[1][3]=fmaf(av.y,wv.w,acc[1][3]);
      acc[2][0]=fmaf(av.z,wv.x,acc[2][0]); acc[2][1]=fmaf(av.z,wv.y,acc[2][1]);
      acc[2][2]=fmaf(av.z,wv.z,acc[2][2]); acc[2][3]=fmaf(av.z,wv.w,acc[2][3]);
      acc[3][0]=fmaf(av.w,wv.x,acc[3][0]); acc[3][1]=fmaf(av.w,wv.y,acc[3][1]);
      acc[3][2]=fmaf(av.w,wv.z,acc[3][2]); acc[3][3]=fmaf(av.w,wv.w,acc[3][3]);
    }
  }
  float b0v = bias[nt+tn+0], b1v = bias[nt+tn+1], b2v = bias[nt+tn+2], b3v = bias[nt+tn+3];
  #pragma unroll
  for (int i=0;i<4;i++){
    float4 o;
    o.x = acc[i][0] + b0v; o.y = acc[i][1] + b1v;
    o.z = acc[i][2] + b2v; o.w = acc[i][3] + b3v;
    *(float4*)(C + (size_t)(mt + tm + i)*Hz + nt + tn) = o;
  }
}

// ---------------------------------------------------------------------------
// Fused attention step, round-6: 1024 threads = 16 waves = 32 groups x 32.
//   q2 = gl_Wq@h+bq                     (wave w: j = w*32..w*32+31)
//   glimpse: ONLINE softmax per group (8 rows each), single gl_ref read,
//            masked rows never loaded; merge via part[32][513]
//   qpt = pt_Wq@qg+bq
//   pointer pass: 32 groups x 8 rows -> slog[]
//   Gumbel-max sample (16-wave reduce)
// Per-row logit fma/shuffle chains identical to round-5 (bit-identical logits).
// ---------------------------------------------------------------------------
__global__ __launch_bounds__(1024) void attn_step(
    const float* __restrict__ gl_Wq, const float* __restrict__ gl_bq,
    const float* __restrict__ gl_V,
    const float* __restrict__ pt_Wq, const float* __restrict__ pt_bq,
    const float* __restrict__ pt_V,
    int t, int hsel2, float* __restrict__ out)
{
  int b = blockIdx.x, tid = threadIdx.x;
  int wave = tid >> 6, lane64 = tid & 63;
  int g = tid >> 5, lane = tid & 31;

  __shared__ __align__(16) float hq[Hz];
  __shared__ __align__(16) float q2s[Hz];
  __shared__ __align__(16) float qgs[Hz];
  __shared__ __align__(16) float qps[Hz];
  __shared__ __align__(16) float vgl[Hz];
  __shared__ __align__(16) float vpt[Hz];
  __shared__ float part[32][513];     // 65.7 KB, 513 stride: conflict-free col merge
  __shared__ float m_arr[32];
  __shared__ float l_arr[32];
  __shared__ float slog[Sz];
  __shared__ float redy[16]; __shared__ int redi[16];
  __shared__ float redm[16]; __shared__ float redsum[16];

  if (tid < Hz){
    hq[tid]  = g_h[(size_t)hsel2*BH + (size_t)b*Hz + tid];
    vgl[tid] = gl_V[tid];
    vpt[tid] = pt_V[tid];
  }
  __syncthreads();

  const unsigned char* mrow = g_mask + b*Sz;

  // ---- q2 = gl_Wq @ h + gl_bq  (wave w: 32 j)
  {
    float hv[8];
    #pragma unroll
    for (int i=0;i<8;i++) hv[i] = hq[lane64*8 + i];
    for (int jj=0;jj<32;jj++){
      int j = wave*32 + jj;
      const float* wr = gl_Wq + (size_t)j*Hz + lane64*8;
      float4 w0 = *(const float4*)wr;
      float4 w1 = *(const float4*)(wr+4);
      float p = 0.f;
      p = fmaf(hv[0], w0.x, p); p = fmaf(hv[1], w0.y, p);
      p = fmaf(hv[2], w0.z, p); p = fmaf(hv[3], w0.w, p);
      p = fmaf(hv[4], w1.x, p); p = fmaf(hv[5], w1.y, p);
      p = fmaf(hv[6], w1.z, p); p = fmaf(hv[7], w1.w, p);
      #pragma unroll
      for (int off=32; off; off>>=1) p += __shfl_xor(p, off);
      if (lane64 == 0) q2s[j] = p + gl_bq[j];
    }
  }
  __syncthreads();

  // ---- glimpse: online softmax, group g owns rows g*8 .. g*8+7
  const float* glbase = g_glref + (size_t)b*Sz*Hz;
  {
    float m_g = -INFINITY, l_g = 0.f;
    float4 racc[4];
    { float4 z = {0.f,0.f,0.f,0.f}; racc[0]=z; racc[1]=z; racc[2]=z; racc[3]=z; }

    for (int r = 0; r < 8; r++){
      int s = g*8 + r;
      if (mrow[s]) continue;                 // exp(-1e9 - m) == 0: skip entirely
      const float4* row4 = (const float4*)(glbase + (size_t)s*Hz);
      float4 x0 = row4[lane], x1 = row4[lane+32], x2 = row4[lane+64], x3 = row4[lane+96];
      // logit (identical chain to r5 pass1)
      float p = 0.f;
      {
        float4 q, vv;
        q = *(const float4*)&q2s[lane*4];        vv = *(const float4*)&vgl[lane*4];
        p = fmaf(vv.x, tanhf(q.x + x0.x), p); p = fmaf(vv.y, tanhf(q.y + x0.y), p);
        p = fmaf(vv.z, tanhf(q.z + x0.z), p); p = fmaf(vv.w, tanhf(q.w + x0.w), p);
        q = *(const float4*)&q2s[(lane+32)*4];   vv = *(const float4*)&vgl[(lane+32)*4];
        p = fmaf(vv.x, tanhf(q.x + x1.x), p); p = fmaf(vv.y, tanhf(q.y + x1.y), p);
        p = fmaf(vv.z, tanhf(q.z + x1.z), p); p = fmaf(vv.w, tanhf(q.w + x1.w), p);
        q = *(const float4*)&q2s[(lane+64)*4];   vv = *(const float4*)&vgl[(lane+64)*4];
        p = fmaf(vv.x, tanhf(q.x + x2.x), p); p = fmaf(vv.y, tanhf(q.y + x2.y), p);
        p = fmaf(vv.z, tanhf(q.z + x2.z), p); p = fmaf(vv.w, tanhf(q.w + x2.w), p);
        q = *(const float4*)&q2s[(lane+96)*4];   vv = *(const float4*)&vgl[(lane+96)*4];
        p = fmaf(vv.x, tanhf(q.x + x3.x), p); p = fmaf(vv.y, tanhf(q.y + x3.y), p);
        p = fmaf(vv.z, tanhf(q.z + x3.z), p); p = fmaf(vv.w, tanhf(q.w + x3.w), p);
      }
      #pragma unroll
      for (int off=16; off; off>>=1) p += __shfl_xor(p, off, 32);
      float lgv = p;                          // group-uniform
      // online update
      if (lgv > m_g){
        float r_ = expf(m_g - lgv);           // m_g=-inf -> 0
        l_g *= r_;
        racc[0].x*=r_; racc[0].y*=r_; racc[0].z*=r_; racc[0].w*=r_;
        racc[1].x*=r_; racc[1].y*=r_; racc[1].z*=r_; racc[1].w*=r_;
        racc[2].x*=r_; racc[2].y*=r_; racc[2].z*=r_; racc[2].w*=r_;
        racc[3].x*=r_; racc[3].y*=r_; racc[3].z*=r_; racc[3].w*=r_;
        m_g = lgv;
      }
      float pr = expf(lgv - m_g);
      l_g += pr;
      racc[0].x=fmaf(pr,x0.x,racc[0].x); racc[0].y=fmaf(pr,x0.y,racc[0].y);
      racc[0].z=fmaf(pr,x0.z,racc[0].z); racc[0].w=fmaf(pr,x0.w,racc[0].w);
      racc[1].x=fmaf(pr,x1.x,racc[1].x); racc[1].y=fmaf(pr,x1.y,racc[1].y);
      racc[1].z=fmaf(pr,x1.z,racc[1].z); racc[1].w=fmaf(pr,x1.w,racc[1].w);
      racc[2].x=fmaf(pr,x2.x,racc[2].x); racc[2].y=fmaf(pr,x2.y,racc[2].y);
      racc[2].z=fmaf(pr,x2.z,racc[2].z); racc[2].w=fmaf(pr,x2.w,racc[2].w);
      racc[3].x=fmaf(pr,x3.x,racc[3].x); racc[3].y=fmaf(pr,x3.y,racc[3].y);
      racc[3].z=fmaf(pr,x3.z,racc[3].z); racc[3].w=fmaf(pr,x3.w,racc[3].w);
    }
    if (lane == 0){ m_arr[g] = m_g; l_arr[g] = l_g; }
    // element index = 4*lane + 128*i + c
    part[g][4*lane+  0] = racc[0].x; part[g][4*lane+  1] = racc[0].y;
    part[g][4*lane+  2] = racc[0].z; part[g][4*lane+  3] = racc[0].w;
    part[g][4*lane+128] = racc[1].x; part[g][4*lane+129] = racc[1].y;
    part[g][4*lane+130] = racc[1].z; part[g][4*lane+131] = racc[1].w;
    part[g][4*lane+256] = racc[2].x; part[g][4*lane+257] = racc[2].y;
    part[g][4*lane+258] = racc[2].z; part[g][4*lane+259] = racc[2].w;
    part[g][4*lane+384] = racc[3].x; part[g][4*lane+385] = racc[3].y;
    part[g][4*lane+386] = racc[3].z; part[g][4*lane+387] = racc[3].w;
  }
  __syncthreads();

  // ---- merge group partials -> qg
  if (tid < Hz){
    float M = m_arr[0];
    #pragma unroll
    for (int gg=1; gg<32; gg++) M = fmaxf(M, m_arr[gg]);
    float num = 0.f, den = 0.f;
    #pragma unroll
    for (int gg=0; gg<32; gg++){
      float w = expf(m_arr[gg] - M);
      num = fmaf(w, part[gg][tid], num);
      den = fmaf(w, l_arr[gg], den);
    }
    qgs[tid] = num / den;
  }
  __syncthreads();

  // ---- qpt = pt_Wq @ qg + pt_bq
  {
    float qv[8];
    #pragma unroll
    for (int i=0;i<8;i++) qv[i] = qgs[lane64*8 + i];
    for (int jj=0;jj<32;jj++){
      int j = wave*32 + jj;
      const float* wr = pt_Wq + (size_t)j*Hz + lane64*8;
      float4 w0 = *(const float4*)wr;
      float4 w1 = *(const float4*)(wr+4);
      float p = 0.f;
      p = fmaf(qv[0], w0.x, p); p = fmaf(qv[1], w0.y, p);
      p = fmaf(qv[2], w0.z, p); p = fmaf(qv[3], w0.w, p);
      p = fmaf(qv[4], w1.x, p); p = fmaf(qv[5], w1.y, p);
      p = fmaf(qv[6], w1.z, p); p = fmaf(qv[7], w1.w, p);
      #pragma unroll
      for (int off=32; off; off>>=1) p += __shfl_xor(p, off);
      if (lane64 == 0) qps[j] = p + pt_bq[j];
    }
  }
  __syncthreads();

  // ---- pointer pass: group g rows g*8..g*8+7 -> slog
  const float* ptbase = g_ptref + (size_t)b*Sz*Hz;
  for (int r = 0; r < 8; r++){
    int s = g*8 + r;
    float lgv;
    if (mrow[s]) lgv = NEGV;
    else {
      const float4* row4 = (const float4*)(ptbase + (size_t)s*Hz);
      float p = 0.f;
      #pragma unroll
      for (int i=0;i<4;i++){
        int idx = lane + i*32;
        float4 x  = row4[idx];
        float4 q  = *(const float4*)&qps[idx*4];
        float4 vv = *(const float4*)&vpt[idx*4];
        p = fmaf(vv.x, tanhf(q.x + x.x), p);
        p = fmaf(vv.y, tanhf(q.y + x.y), p);
        p = fmaf(vv.z, tanhf(q.z + x.z), p);
        p = fmaf(vv.w, tanhf(q.w + x.w), p);
      }
      #pragma unroll
      for (int off=16; off; off>>=1) p += __shfl_xor(p, off, 32);
      lgv = 10.f * tanhf(p);
    }
    if (lane == 0) slog[s] = lgv;
  }
  __syncthreads();

  // ---- Gumbel-max sample (threads 0..255 own s = tid)
  float lg = NEGV, y = -INFINITY;
  if (tid < Sz){
    lg = slog[tid];
    unsigned bits = rng_bits(g_keys[2*t], g_keys[2*t+1], (unsigned)(b*Sz + tid));
    float u = __uint_as_float((bits >> 9) | 0x3f800000u) - 1.f;
    float gum = -logf(-logf(u + 1e-10f) + 1e-10f);
    y = lg + gum;
  }
  float by = y; int bi = tid; float bm = lg;
  #pragma unroll
  for (int off=32; off; off>>=1){
    float oy = __shfl_xor(by, off);
    int   oi = __shfl_xor(bi, off);
    float om = __shfl_xor(bm, off);
    if (oy > by || (oy == by && oi < bi)){ by = oy; bi = oi; }
    bm = fmaxf(bm, om);
  }
  if (lane64 == 0){ redy[wave] = by; redi[wave] = bi; redm[wave] = bm; }
  __syncthreads();
  float fy = redy[0]; int fi = redi[0]; float fm = redm[0];
  #pragma unroll
  for (int w=1; w<16; w++){
    if (redy[w] > fy || (redy[w] == fy && redi[w] < fi)){ fy = redy[w]; fi = redi[w]; }
    fm = fmaxf(fm, redm[w]);
  }
  int ptr = fi;

  float pe = (tid < Sz) ? expf(lg - fm) : 0.f;
  #pragma unroll
  for (int off=32; off; off>>=1) pe += __shfl_xor(pe, off);
  if (lane64 == 0) redsum[wave] = pe;
  __syncthreads();
  if (tid == 0){
    float den = 0.f;
    #pragma unroll
    for (int w=0; w<16; w++) den += redsum[w];
    float logp = slog[ptr] - fm - logf(den);
    out[(size_t)b*Sz + t] = (float)ptr;
    out[(size_t)Bz*Sz + (size_t)b*Sz + t] = logp;
    g_mask[b*Sz + ptr] = 1;
    g_ptrbuf[b] = ptr;
  }
}

// ---------------------------------------------------------------------------
extern "C" void kernel_launch(void* const* d_in, const int* in_sizes, int n_in,
                              void* d_out, int out_size, void* d_ws, size_t ws_size,
                              hipStream_t stream){
  (void)in_sizes; (void)n_in; (void)out_size; (void)d_ws; (void)ws_size;
  const float* embedding = (const float*)d_in[0];
  const float* enc_Wih = (const float*)d_in[1];
  const float* enc_Whh = (const float*)d_in[2];
  const float* enc_b   = (const float*)d_in[3];
  const float* dec_Wih = (const float*)d_in[4];
  const float* dec_Whh = (const float*)d_in[5];
  const float* dec_b   = (const float*)d_in[6];
  const float* pt_Wq   = (const float*)d_in[7];
  const float* pt_bq   = (const float*)d_in[8];
  const float* pt_Wref = (const float*)d_in[9];
  const float* pt_bref = (const float*)d_in[10];
  const float* pt_V    = (const float*)d_in[11];
  const float* gl_Wq   = (const float*)d_in[12];
  const float* gl_bq   = (const float*)d_in[13];
  const float* gl_Wref = (const float*)d_in[14];
  const float* gl_bref = (const float*)d_in[15];
  const float* gl_V    = (const float*)d_in[16];
  const float* dec_start = (const float*)d_in[17];
  const int*   inputs  = (const int*)d_in[18];
  float* out = (float*)d_out;

  init_kernel<<<512, 256, 0, stream>>>();

  // ---- encoder ----
  for (int t = 0; t < Sz; t++){
    lstm_step<<<dim3(4,32), 256, 0, stream>>>(enc_Wih, enc_Whh, enc_b,
        embedding, inputs, dec_start, t, 0, t & 1);
  }
  // ---- ref projections ----
  gemm_ref<<<dim3(1024,8), 256, 0, stream>>>(gl_Wref, gl_bref, 1);
  gemm_ref<<<dim3(1024,8), 256, 0, stream>>>(pt_Wref, pt_bref, 2);

  // ---- decoder: 2 kernels per step ----
  for (int t = 0; t < Sz; t++){
    lstm_step<<<dim3(4,32), 256, 0, stream>>>(dec_Wih, dec_Whh, dec_b,
        embedding, inputs, dec_start, t, 1, t & 1);
    attn_step<<<Bz, 1024, 0, stream>>>(gl_Wq, gl_bq, gl_V,
        pt_Wq, pt_bq, pt_V, t, (t+1) & 1, out);
  }
}

// Round 8
// 34792.905 us; speedup vs baseline: 2.9509x; 1.2487x over previous
//
#include <hip/hip_runtime.h>
#include <math.h>

// ---------------------------------------------------------------------------
// PointerNet rollout on MI355X. fp32 throughout (argmax-exactness required).
// Round-8 = round-7 with the host-side __device__-symbol-arg bug fixed:
// xproj_kernel now selects its destination global internally (int dst).
// NEVER pass g_* globals as kernel args from kernel_launch (host shadow!).
// ---------------------------------------------------------------------------

#define Bz 256
#define Sz 256
#define Ez 128
#define Hz 512
#define NEGV -1e9f
#define BH (Bz*Hz)

__device__ float g_encout[Bz*Sz*Hz];
__device__ float g_glref[Bz*Sz*Hz];
__device__ float g_ptref[Bz*Sz*Hz];
__device__ float g_xpe[256*2048];   // enc input projections: bias + emb@Wih^T
__device__ float g_xpd[257*2048];   // dec (row 256 = dec_start)
__device__ float g_h[2*BH];
__device__ float g_c[BH];
__device__ int g_ptrbuf[Bz];
__device__ unsigned g_keys[2*Sz];
__device__ unsigned char g_mask[Bz*Sz];

__device__ __forceinline__ unsigned rotl32(unsigned v, int d){ return (v<<d)|(v>>(32-d)); }

__device__ __forceinline__ void tf2x32(unsigned k0, unsigned k1, unsigned x0, unsigned x1,
                                       unsigned &o0, unsigned &o1){
  unsigned ks2 = k0 ^ k1 ^ 0x1BD11BDAu;
  x0 += k0; x1 += k1;
#define TFR(r) { x0 += x1; x1 = rotl32(x1,(r)); x1 ^= x0; }
  TFR(13) TFR(15) TFR(26) TFR(6)
  x0 += k1; x1 += ks2 + 1u;
  TFR(17) TFR(29) TFR(16) TFR(24)
  x0 += ks2; x1 += k0 + 2u;
  TFR(13) TFR(15) TFR(26) TFR(6)
  x0 += k0; x1 += k1 + 3u;
  TFR(17) TFR(29) TFR(16) TFR(24)
  x0 += k1; x1 += ks2 + 4u;
  TFR(13) TFR(15) TFR(26) TFR(6)
  x0 += ks2; x1 += k0 + 5u;
#undef TFR
  o0 = x0; o1 = x1;
}

__device__ __forceinline__ unsigned rng_bits(unsigned ka, unsigned kb, unsigned idx){
  unsigned o0,o1; tf2x32(ka,kb, 0u, idx, o0,o1);
  return o0 ^ o1;
}

// ---------------------------------------------------------------------------
__global__ __launch_bounds__(256) void init_kernel(){
  int i = blockIdx.x*256 + threadIdx.x;
  if (i < BH){ g_h[i] = 0.f; g_c[i] = 0.f; }
  if (i < Bz*Sz) g_mask[i] = 0;
  if (i < Sz){
    unsigned o0,o1; tf2x32(0u,1u, 0u, (unsigned)i, o0,o1);
    g_keys[2*i] = o0; g_keys[2*i+1] = o1;
  }
}

// ---------------------------------------------------------------------------
// Xp[c][row] = bias[row] + sum_k emb[c][k]*Wih[row][k], k ascending from bias
// (identical association to the r3 passing kernel's x-part).
// grid (ncity, 8) x 256 thr; c==256 uses dec_start. dst: 0 -> g_xpe, 1 -> g_xpd.
// ---------------------------------------------------------------------------
__global__ __launch_bounds__(256) void xproj_kernel(
    const float* __restrict__ Wih, const float* __restrict__ bias,
    const float* __restrict__ emb, const float* __restrict__ dstart,
    int dst)
{
  float* Xp = dst ? g_xpd : g_xpe;
  int c = blockIdx.x;
  int row = blockIdx.y*256 + threadIdx.x;
  __shared__ float xs[Ez];
  if (threadIdx.x < Ez) xs[threadIdx.x] = (c < 256) ? emb[c*Ez + threadIdx.x]
                                                    : dstart[threadIdx.x];
  __syncthreads();
  float a = bias[row];
  const float* w = Wih + (size_t)row*Ez;
  #pragma unroll 8
  for (int k = 0; k < Ez; k++) a = fmaf(xs[k], w[k], a);
  Xp[(size_t)c*2048 + row] = a;
}

// ---------------------------------------------------------------------------
// LSTM step v4: gates = Xp[city] + h@Whh^T (K=512), k-ascending (bit-identical
// to r3). grid (8,32) = 256 blocks, 256 thr; block = 32 b x 64 gate-rows;
// thread = 2 b x 4 gates.
// ---------------------------------------------------------------------------
__global__ __launch_bounds__(256) void lstm_step(
    const float* __restrict__ Whh,   // [2048][512]
    const int*   __restrict__ inputs,// [Bz][Sz]
    int t, int is_dec, int hsel)
{
  __shared__ float A_lds[32][36];   // [b][k]
  __shared__ float W_lds[64][36];   // [row][k], row = gate*16 + jj

  const float* h_in = g_h + (size_t)hsel*BH;
  float*       h_out = g_h + (size_t)(hsel^1)*BH;
  const float* Xp = is_dec ? g_xpd : g_xpe;

  int tid = threadIdx.x;
  int bt = blockIdx.x;     // 0..7 (32 b)
  int jt = blockIdx.y;     // 0..31 (16 j)
  int jj = tid & 15;
  int bp = tid >> 4;       // 0..15
  int jglob = jt*16 + jj;

  int bA = bt*32 + bp*2, bB = bA + 1;
  int cA, cB;
  if (is_dec){
    if (t == 0){ cA = 256; cB = 256; }
    else { cA = inputs[bA*Sz + g_ptrbuf[bA]]; cB = inputs[bB*Sz + g_ptrbuf[bB]]; }
  } else {
    cA = inputs[bA*Sz + t]; cB = inputs[bB*Sz + t];
  }

  float acc[2][4];
  {
    const float* xa = Xp + (size_t)cA*2048;
    const float* xb = Xp + (size_t)cB*2048;
    #pragma unroll
    for (int g=0; g<4; g++){
      acc[0][g] = xa[g*Hz + jglob];
      acc[1][g] = xb[g*Hz + jglob];
    }
  }

  int sr = tid >> 3;          // 0..31 A staging row (b)
  int sk = (tid & 7) * 4;     // A k offset (float4)
  int wr = tid >> 2;          // 0..63 W staging row
  int wk = (tid & 3) * 8;     // W k offset (2 float4)
  int bg = bt*32 + sr;
  int wrow_g = (wr >> 4)*Hz + jt*16 + (wr & 15);

  for (int kc = 0; kc < 16; kc++){
    int k0 = kc*32;
    __syncthreads();
    {
      float4 av = *(const float4*)(h_in + (size_t)bg*Hz + k0 + sk);
      *(float4*)&A_lds[sr][sk] = av;
    }
    {
      const float* ws = Whh + (size_t)wrow_g*Hz + k0 + wk;
      float4 w0 = *(const float4*)ws;
      float4 w1 = *(const float4*)(ws + 4);
      *(float4*)&W_lds[wr][wk]     = w0;
      *(float4*)&W_lds[wr][wk + 4] = w1;
    }
    __syncthreads();
    #pragma unroll
    for (int k4 = 0; k4 < 8; k4++){
      float4 w0 = *(const float4*)&W_lds[jj      ][k4*4];
      float4 w1 = *(const float4*)&W_lds[16 + jj ][k4*4];
      float4 w2 = *(const float4*)&W_lds[32 + jj ][k4*4];
      float4 w3 = *(const float4*)&W_lds[48 + jj ][k4*4];
      float4 a0 = *(const float4*)&A_lds[bp*2    ][k4*4];
      float4 a1 = *(const float4*)&A_lds[bp*2 + 1][k4*4];
#define LSTEP(c) \
      acc[0][0]=fmaf(a0.c,w0.c,acc[0][0]); acc[0][1]=fmaf(a0.c,w1.c,acc[0][1]); \
      acc[0][2]=fmaf(a0.c,w2.c,acc[0][2]); acc[0][3]=fmaf(a0.c,w3.c,acc[0][3]); \
      acc[1][0]=fmaf(a1.c,w0.c,acc[1][0]); acc[1][1]=fmaf(a1.c,w1.c,acc[1][1]); \
      acc[1][2]=fmaf(a1.c,w2.c,acc[1][2]); acc[1][3]=fmaf(a1.c,w3.c,acc[1][3]);
      LSTEP(x) LSTEP(y) LSTEP(z) LSTEP(w)
#undef LSTEP
    }
  }

  #pragma unroll
  for (int r=0;r<2;r++){
    int b = bA + r;
    float gi = acc[r][0], gf = acc[r][1], gg = acc[r][2], go = acc[r][3];
    float co = g_c[(size_t)b*Hz + jglob];
    float si = 1.f/(1.f + expf(-gi));
    float sf = 1.f/(1.f + expf(-gf));
    float so = 1.f/(1.f + expf(-go));
    float cn = sf*co + si*tanhf(gg);
    float hn = so*tanhf(cn);
    g_c[(size_t)b*Hz + jglob] = cn;
    h_out[(size_t)b*Hz + jglob] = hn;
    if (!is_dec) g_encout[((size_t)b*Sz + t)*Hz + jglob] = hn;
  }
}

// ---------------------------------------------------------------------------
// ref projections: C[65536][512] = enc_out @ W^T + b. 64x64 tile.
// ---------------------------------------------------------------------------
__global__ __launch_bounds__(256) void gemm_ref(
    const float* __restrict__ W, const float* __restrict__ bias, int dst_id)
{
  const float* A = g_encout;
  float*       C = (dst_id == 1) ? g_glref : g_ptref;
  __shared__ float As[32][68];
  __shared__ float Ws[32][68];
  int tid = threadIdx.x;
  int mt = blockIdx.x * 64, nt = blockIdx.y * 64;
  int tm = (tid & 15) * 4, tn = (tid >> 4) * 4;
  float acc[4][4] = {};
  int lr = tid >> 2;
  int lk = (tid & 3) * 8;

  for (int kc = 0; kc < 16; kc++){
    int k0 = kc*32;
    __syncthreads();
    {
      const float* ar = A + (size_t)(mt + lr)*Hz + k0 + lk;
      float4 a0 = *(const float4*)ar, a1 = *(const float4*)(ar+4);
      As[lk+0][lr]=a0.x; As[lk+1][lr]=a0.y; As[lk+2][lr]=a0.z; As[lk+3][lr]=a0.w;
      As[lk+4][lr]=a1.x; As[lk+5][lr]=a1.y; As[lk+6][lr]=a1.z; As[lk+7][lr]=a1.w;
      const float* wrp = W + (size_t)(nt + lr)*Hz + k0 + lk;
      float4 w0 = *(const float4*)wrp, w1 = *(const float4*)(wrp+4);
      Ws[lk+0][lr]=w0.x; Ws[lk+1][lr]=w0.y; Ws[lk+2][lr]=w0.z; Ws[lk+3][lr]=w0.w;
      Ws[lk+4][lr]=w1.x; Ws[lk+5][lr]=w1.y; Ws[lk+6][lr]=w1.z; Ws[lk+7][lr]=w1.w;
    }
    __syncthreads();
    #pragma unroll
    for (int k=0;k<32;k++){
      float4 av = *(const float4*)&As[k][tm];
      float4 wv = *(const float4*)&Ws[k][tn];
      acc[0][0]=fmaf(av.x,wv.x,acc[0][0]); acc[0][1]=fmaf(av.x,wv.y,acc[0][1]);
      acc[0][2]=fmaf(av.x,wv.z,acc[0][2]); acc[0][3]=fmaf(av.x,wv.w,acc[0][3]);
      acc[1][0]=fmaf(av.y,wv.x,acc[1][0]); acc[1][1]=fmaf(av.y,wv.y,acc[1][1]);
      acc[1][2]=fmaf(av.y,wv.z,acc[1][2]); acc[1][3]=fmaf(av.y,wv.w,acc[1][3]);
      acc[2][0]=fmaf(av.z,wv.x,acc[2][0]); acc[2][1]=fmaf(av.z,wv.y,acc[2][1]);
      acc[2][2]=fmaf(av.z,wv.z,acc[2][2]); acc[2][3]=fmaf(av.z,wv.w,acc[2][3]);
      acc[3][0]=fmaf(av.w,wv.x,acc[3][0]); acc[3][1]=fmaf(av.w,wv.y,acc[3][1]);
      acc[3][2]=fmaf(av.w,wv.z,acc[3][2]); acc[3][3]=fmaf(av.w,wv.w,acc[3][3]);
    }
  }
  float b0v = bias[nt+tn+0], b1v = bias[nt+tn+1], b2v = bias[nt+tn+2], b3v = bias[nt+tn+3];
  #pragma unroll
  for (int i=0;i<4;i++){
    float4 o;
    o.x = acc[i][0] + b0v; o.y = acc[i][1] + b1v;
    o.z = acc[i][2] + b2v; o.w = acc[i][3] + b3v;
    *(float4*)(C + (size_t)(mt + tm + i)*Hz + nt + tn) = o;
  }
}

// ---------------------------------------------------------------------------
// Fused attention step: 512 threads = 8 waves = 16 groups x 32 lanes.
// Ballot-compacted unmasked-row lists + depth-1 prefetch in both streaming
// passes; unroll-2 MVMs. Per-row logit chains identical to r5/r6 (bit-exact).
// ---------------------------------------------------------------------------
__global__ __launch_bounds__(512) void attn_step(
    const float* __restrict__ gl_Wq, const float* __restrict__ gl_bq,
    const float* __restrict__ gl_V,
    const float* __restrict__ pt_Wq, const float* __restrict__ pt_bq,
    const float* __restrict__ pt_V,
    int t, int hsel2, float* __restrict__ out)
{
  int b = blockIdx.x, tid = threadIdx.x;
  int wave = tid >> 6, lane64 = tid & 63;
  int g = tid >> 5, lane = tid & 31;

  __shared__ __align__(16) float hq[Hz];
  __shared__ __align__(16) float q2s[Hz];
  __shared__ __align__(16) float qgs[Hz];
  __shared__ __align__(16) float qps[Hz];
  __shared__ __align__(16) float vgl[Hz];
  __shared__ __align__(16) float vpt[Hz];
  __shared__ float part[16][513];     // 32.8 KB
  __shared__ float m_arr[16];
  __shared__ float l_arr[16];
  __shared__ int   rlist[16][16];
  __shared__ float slog[Sz];
  __shared__ float redy[8]; __shared__ int redi[8];
  __shared__ float redm[8]; __shared__ float redsum[8];

  hq[tid]  = g_h[(size_t)hsel2*BH + (size_t)b*Hz + tid];
  vgl[tid] = gl_V[tid];
  vpt[tid] = pt_V[tid];
  __syncthreads();

  const unsigned char* mrow = g_mask + b*Sz;

  // ---- compacted row list per group (group g owns rows g*16..g*16+15)
  int cnt;
  {
    bool un = (lane < 16) ? (mrow[g*16 + lane] == 0) : false;
    unsigned long long bal = __ballot(un);
    unsigned m16 = (unsigned)((g & 1) ? (bal >> 32) : bal) & 0xFFFFu;
    cnt = __popc(m16);
    if (lane < 16){
      if (un){
        int rank = __popc(m16 & ((1u << lane) - 1u));
        rlist[g][rank] = g*16 + lane;
      } else {
        slog[g*16 + lane] = NEGV;    // pre-fill masked logits
      }
    }
  }

  // ---- q2 = gl_Wq @ h + gl_bq  (wave w: j = w*64..w*64+63, unroll 2)
  {
    float hv[8];
    #pragma unroll
    for (int i=0;i<8;i++) hv[i] = hq[lane64*8 + i];
    for (int jj=0;jj<64;jj+=2){
      int j0 = wave*64 + jj;
      const float* wr0 = gl_Wq + (size_t)j0*Hz + lane64*8;
      const float* wr1 = wr0 + Hz;
      float4 A0 = *(const float4*)wr0, A1 = *(const float4*)(wr0+4);
      float4 B0 = *(const float4*)wr1, B1 = *(const float4*)(wr1+4);
      float p0 = 0.f, p1 = 0.f;
      p0 = fmaf(hv[0], A0.x, p0); p0 = fmaf(hv[1], A0.y, p0);
      p0 = fmaf(hv[2], A0.z, p0); p0 = fmaf(hv[3], A0.w, p0);
      p0 = fmaf(hv[4], A1.x, p0); p0 = fmaf(hv[5], A1.y, p0);
      p0 = fmaf(hv[6], A1.z, p0); p0 = fmaf(hv[7], A1.w, p0);
      p1 = fmaf(hv[0], B0.x, p1); p1 = fmaf(hv[1], B0.y, p1);
      p1 = fmaf(hv[2], B0.z, p1); p1 = fmaf(hv[3], B0.w, p1);
      p1 = fmaf(hv[4], B1.x, p1); p1 = fmaf(hv[5], B1.y, p1);
      p1 = fmaf(hv[6], B1.z, p1); p1 = fmaf(hv[7], B1.w, p1);
      #pragma unroll
      for (int off=32; off; off>>=1) p0 += __shfl_xor(p0, off);
      #pragma unroll
      for (int off=32; off; off>>=1) p1 += __shfl_xor(p1, off);
      if (lane64 == 0){ q2s[j0] = p0 + gl_bq[j0]; q2s[j0+1] = p1 + gl_bq[j0+1]; }
    }
  }
  __syncthreads();

  // ---- glimpse: online softmax over compacted rows, depth-1 prefetch
  const float* glbase = g_glref + (size_t)b*Sz*Hz;
  {
    float m_g = -INFINITY, l_g = 0.f;
    float4 racc[4];
    { float4 z = {0.f,0.f,0.f,0.f}; racc[0]=z; racc[1]=z; racc[2]=z; racc[3]=z; }

    float4 xn0, xn1, xn2, xn3;
    if (cnt > 0){
      const float4* rp = (const float4*)(glbase + (size_t)rlist[g][0]*Hz);
      xn0 = rp[lane]; xn1 = rp[lane+32]; xn2 = rp[lane+64]; xn3 = rp[lane+96];
    }
    for (int i = 0; i < cnt; i++){
      float4 x0 = xn0, x1 = xn1, x2 = xn2, x3 = xn3;
      if (i + 1 < cnt){
        const float4* rp = (const float4*)(glbase + (size_t)rlist[g][i+1]*Hz);
        xn0 = rp[lane]; xn1 = rp[lane+32]; xn2 = rp[lane+64]; xn3 = rp[lane+96];
      }
      // logit (chain identical to r5/r6)
      float p = 0.f;
      {
        float4 q, vv;
        q = *(const float4*)&q2s[lane*4];        vv = *(const float4*)&vgl[lane*4];
        p = fmaf(vv.x, tanhf(q.x + x0.x), p); p = fmaf(vv.y, tanhf(q.y + x0.y), p);
        p = fmaf(vv.z, tanhf(q.z + x0.z), p); p = fmaf(vv.w, tanhf(q.w + x0.w), p);
        q = *(const float4*)&q2s[(lane+32)*4];   vv = *(const float4*)&vgl[(lane+32)*4];
        p = fmaf(vv.x, tanhf(q.x + x1.x), p); p = fmaf(vv.y, tanhf(q.y + x1.y), p);
        p = fmaf(vv.z, tanhf(q.z + x1.z), p); p = fmaf(vv.w, tanhf(q.w + x1.w), p);
        q = *(const float4*)&q2s[(lane+64)*4];   vv = *(const float4*)&vgl[(lane+64)*4];
        p = fmaf(vv.x, tanhf(q.x + x2.x), p); p = fmaf(vv.y, tanhf(q.y + x2.y), p);
        p = fmaf(vv.z, tanhf(q.z + x2.z), p); p = fmaf(vv.w, tanhf(q.w + x2.w), p);
        q = *(const float4*)&q2s[(lane+96)*4];   vv = *(const float4*)&vgl[(lane+96)*4];
        p = fmaf(vv.x, tanhf(q.x + x3.x), p); p = fmaf(vv.y, tanhf(q.y + x3.y), p);
        p = fmaf(vv.z, tanhf(q.z + x3.z), p); p = fmaf(vv.w, tanhf(q.w + x3.w), p);
      }
      #pragma unroll
      for (int off=16; off; off>>=1) p += __shfl_xor(p, off, 32);
      float lgv = p;
      if (lgv > m_g){
        float r_ = expf(m_g - lgv);
        l_g *= r_;
        racc[0].x*=r_; racc[0].y*=r_; racc[0].z*=r_; racc[0].w*=r_;
        racc[1].x*=r_; racc[1].y*=r_; racc[1].z*=r_; racc[1].w*=r_;
        racc[2].x*=r_; racc[2].y*=r_; racc[2].z*=r_; racc[2].w*=r_;
        racc[3].x*=r_; racc[3].y*=r_; racc[3].z*=r_; racc[3].w*=r_;
        m_g = lgv;
      }
      float pr = expf(lgv - m_g);
      l_g += pr;
      racc[0].x=fmaf(pr,x0.x,racc[0].x); racc[0].y=fmaf(pr,x0.y,racc[0].y);
      racc[0].z=fmaf(pr,x0.z,racc[0].z); racc[0].w=fmaf(pr,x0.w,racc[0].w);
      racc[1].x=fmaf(pr,x1.x,racc[1].x); racc[1].y=fmaf(pr,x1.y,racc[1].y);
      racc[1].z=fmaf(pr,x1.z,racc[1].z); racc[1].w=fmaf(pr,x1.w,racc[1].w);
      racc[2].x=fmaf(pr,x2.x,racc[2].x); racc[2].y=fmaf(pr,x2.y,racc[2].y);
      racc[2].z=fmaf(pr,x2.z,racc[2].z); racc[2].w=fmaf(pr,x2.w,racc[2].w);
      racc[3].x=fmaf(pr,x3.x,racc[3].x); racc[3].y=fmaf(pr,x3.y,racc[3].y);
      racc[3].z=fmaf(pr,x3.z,racc[3].z); racc[3].w=fmaf(pr,x3.w,racc[3].w);
    }
    if (lane == 0){ m_arr[g] = m_g; l_arr[g] = l_g; }
    part[g][4*lane+  0] = racc[0].x; part[g][4*lane+  1] = racc[0].y;
    part[g][4*lane+  2] = racc[0].z; part[g][4*lane+  3] = racc[0].w;
    part[g][4*lane+128] = racc[1].x; part[g][4*lane+129] = racc[1].y;
    part[g][4*lane+130] = racc[1].z; part[g][4*lane+131] = racc[1].w;
    part[g][4*lane+256] = racc[2].x; part[g][4*lane+257] = racc[2].y;
    part[g][4*lane+258] = racc[2].z; part[g][4*lane+259] = racc[2].w;
    part[g][4*lane+384] = racc[3].x; part[g][4*lane+385] = racc[3].y;
    part[g][4*lane+386] = racc[3].z; part[g][4*lane+387] = racc[3].w;
  }
  __syncthreads();

  // ---- merge group partials -> qg
  {
    float M = m_arr[0];
    #pragma unroll
    for (int gg=1; gg<16; gg++) M = fmaxf(M, m_arr[gg]);
    float num = 0.f, den = 0.f;
    #pragma unroll
    for (int gg=0; gg<16; gg++){
      float w = expf(m_arr[gg] - M);
      num = fmaf(w, part[gg][tid], num);
      den = fmaf(w, l_arr[gg], den);
    }
    qgs[tid] = num / den;
  }
  __syncthreads();

  // ---- qpt = pt_Wq @ qg + pt_bq (unroll 2)
  {
    float qv[8];
    #pragma unroll
    for (int i=0;i<8;i++) qv[i] = qgs[lane64*8 + i];
    for (int jj=0;jj<64;jj+=2){
      int j0 = wave*64 + jj;
      const float* wr0 = pt_Wq + (size_t)j0*Hz + lane64*8;
      const float* wr1 = wr0 + Hz;
      float4 A0 = *(const float4*)wr0, A1 = *(const float4*)(wr0+4);
      float4 B0 = *(const float4*)wr1, B1 = *(const float4*)(wr1+4);
      float p0 = 0.f, p1 = 0.f;
      p0 = fmaf(qv[0], A0.x, p0); p0 = fmaf(qv[1], A0.y, p0);
      p0 = fmaf(qv[2], A0.z, p0); p0 = fmaf(qv[3], A0.w, p0);
      p0 = fmaf(qv[4], A1.x, p0); p0 = fmaf(qv[5], A1.y, p0);
      p0 = fmaf(qv[6], A1.z, p0); p0 = fmaf(qv[7], A1.w, p0);
      p1 = fmaf(qv[0], B0.x, p1); p1 = fmaf(qv[1], B0.y, p1);
      p1 = fmaf(qv[2], B0.z, p1); p1 = fmaf(qv[3], B0.w, p1);
      p1 = fmaf(qv[4], B1.x, p1); p1 = fmaf(qv[5], B1.y, p1);
      p1 = fmaf(qv[6], B1.z, p1); p1 = fmaf(qv[7], B1.w, p1);
      #pragma unroll
      for (int off=32; off; off>>=1) p0 += __shfl_xor(p0, off);
      #pragma unroll
      for (int off=32; off; off>>=1) p1 += __shfl_xor(p1, off);
      if (lane64 == 0){ qps[j0] = p0 + pt_bq[j0]; qps[j0+1] = p1 + pt_bq[j0+1]; }
    }
  }
  __syncthreads();

  // ---- pointer pass: compacted rows, depth-1 prefetch
  const float* ptbase = g_ptref + (size_t)b*Sz*Hz;
  {
    float4 xn0, xn1, xn2, xn3;
    if (cnt > 0){
      const float4* rp = (const float4*)(ptbase + (size_t)rlist[g][0]*Hz);
      xn0 = rp[lane]; xn1 = rp[lane+32]; xn2 = rp[lane+64]; xn3 = rp[lane+96];
    }
    for (int i = 0; i < cnt; i++){
      int s = rlist[g][i];
      float4 x0 = xn0, x1 = xn1, x2 = xn2, x3 = xn3;
      if (i + 1 < cnt){
        const float4* rp = (const float4*)(ptbase + (size_t)rlist[g][i+1]*Hz);
        xn0 = rp[lane]; xn1 = rp[lane+32]; xn2 = rp[lane+64]; xn3 = rp[lane+96];
      }
      float p = 0.f;
      {
        float4 q, vv;
        q = *(const float4*)&qps[lane*4];        vv = *(const float4*)&vpt[lane*4];
        p = fmaf(vv.x, tanhf(q.x + x0.x), p); p = fmaf(vv.y, tanhf(q.y + x0.y), p);
        p = fmaf(vv.z, tanhf(q.z + x0.z), p); p = fmaf(vv.w, tanhf(q.w + x0.w), p);
        q = *(const float4*)&qps[(lane+32)*4];   vv = *(const float4*)&vpt[(lane+32)*4];
        p = fmaf(vv.x, tanhf(q.x + x1.x), p); p = fmaf(vv.y, tanhf(q.y + x1.y), p);
        p = fmaf(vv.z, tanhf(q.z + x1.z), p); p = fmaf(vv.w, tanhf(q.w + x1.w), p);
        q = *(const float4*)&qps[(lane+64)*4];   vv = *(const float4*)&vpt[(lane+64)*4];
        p = fmaf(vv.x, tanhf(q.x + x2.x), p); p = fmaf(vv.y, tanhf(q.y + x2.y), p);
        p = fmaf(vv.z, tanhf(q.z + x2.z), p); p = fmaf(vv.w, tanhf(q.w + x2.w), p);
        q = *(const float4*)&qps[(lane+96)*4];   vv = *(const float4*)&vpt[(lane+96)*4];
        p = fmaf(vv.x, tanhf(q.x + x3.x), p); p = fmaf(vv.y, tanhf(q.y + x3.y), p);
        p = fmaf(vv.z, tanhf(q.z + x3.z), p); p = fmaf(vv.w, tanhf(q.w + x3.w), p);
      }
      #pragma unroll
      for (int off=16; off; off>>=1) p += __shfl_xor(p, off, 32);
      if (lane == 0) slog[s] = 10.f * tanhf(p);
    }
  }
  __syncthreads();

  // ---- Gumbel-max sample (threads 0..255 own s = tid) — r5 verbatim
  float lg = NEGV, y = -INFINITY;
  if (tid < Sz){
    lg = slog[tid];
    unsigned bits = rng_bits(g_keys[2*t], g_keys[2*t+1], (unsigned)(b*Sz + tid));
    float u = __uint_as_float((bits >> 9) | 0x3f800000u) - 1.f;
    float gum = -logf(-logf(u + 1e-10f) + 1e-10f);
    y = lg + gum;
  }
  float by = y; int bi = tid; float bm = lg;
  #pragma unroll
  for (int off=32; off; off>>=1){
    float oy = __shfl_xor(by, off);
    int   oi = __shfl_xor(bi, off);
    float om = __shfl_xor(bm, off);
    if (oy > by || (oy == by && oi < bi)){ by = oy; bi = oi; }
    bm = fmaxf(bm, om);
  }
  if (lane64 == 0){ redy[wave] = by; redi[wave] = bi; redm[wave] = bm; }
  __syncthreads();
  float fy = redy[0]; int fi = redi[0]; float fm = redm[0];
  #pragma unroll
  for (int w=1; w<8; w++){
    if (redy[w] > fy || (redy[w] == fy && redi[w] < fi)){ fy = redy[w]; fi = redi[w]; }
    fm = fmaxf(fm, redm[w]);
  }
  int ptr = fi;

  float pe = (tid < Sz) ? expf(lg - fm) : 0.f;
  #pragma unroll
  for (int off=32; off; off>>=1) pe += __shfl_xor(pe, off);
  if (lane64 == 0) redsum[wave] = pe;
  __syncthreads();
  if (tid == 0){
    float den = ((redsum[0]+redsum[1]) + (redsum[2]+redsum[3]))
              + ((redsum[4]+redsum[5]) + (redsum[6]+redsum[7]));
    float logp = slog[ptr] - fm - logf(den);
    out[(size_t)b*Sz + t] = (float)ptr;
    out[(size_t)Bz*Sz + (size_t)b*Sz + t] = logp;
    g_mask[b*Sz + ptr] = 1;
    g_ptrbuf[b] = ptr;
  }
}

// ---------------------------------------------------------------------------
extern "C" void kernel_launch(void* const* d_in, const int* in_sizes, int n_in,
                              void* d_out, int out_size, void* d_ws, size_t ws_size,
                              hipStream_t stream){
  (void)in_sizes; (void)n_in; (void)out_size; (void)d_ws; (void)ws_size;
  const float* embedding = (const float*)d_in[0];
  const float* enc_Wih = (const float*)d_in[1];
  const float* enc_Whh = (const float*)d_in[2];
  const float* enc_b   = (const float*)d_in[3];
  const float* dec_Wih = (const float*)d_in[4];
  const float* dec_Whh = (const float*)d_in[5];
  const float* dec_b   = (const float*)d_in[6];
  const float* pt_Wq   = (const float*)d_in[7];
  const float* pt_bq   = (const float*)d_in[8];
  const float* pt_Wref = (const float*)d_in[9];
  const float* pt_bref = (const float*)d_in[10];
  const float* pt_V    = (const float*)d_in[11];
  const float* gl_Wq   = (const float*)d_in[12];
  const float* gl_bq   = (const float*)d_in[13];
  const float* gl_Wref = (const float*)d_in[14];
  const float* gl_bref = (const float*)d_in[15];
  const float* gl_V    = (const float*)d_in[16];
  const float* dec_start = (const float*)d_in[17];
  const int*   inputs  = (const int*)d_in[18];
  float* out = (float*)d_out;

  init_kernel<<<512, 256, 0, stream>>>();
  // input-projection tables (dst selected INSIDE the kernel — no device
  // symbols as host args!)
  xproj_kernel<<<dim3(256,8), 256, 0, stream>>>(enc_Wih, enc_b, embedding, dec_start, 0);
  xproj_kernel<<<dim3(257,8), 256, 0, stream>>>(dec_Wih, dec_b, embedding, dec_start, 1);

  // ---- encoder ----
  for (int t = 0; t < Sz; t++){
    lstm_step<<<dim3(8,32), 256, 0, stream>>>(enc_Whh, inputs, t, 0, t & 1);
  }
  // ---- ref projections ----
  gemm_ref<<<dim3(1024,8), 256, 0, stream>>>(gl_Wref, gl_bref, 1);
  gemm_ref<<<dim3(1024,8), 256, 0, stream>>>(pt_Wref, pt_bref, 2);

  // ---- decoder: 2 kernels per step ----
  for (int t = 0; t < Sz; t++){
    lstm_step<<<dim3(8,32), 256, 0, stream>>>(dec_Whh, inputs, t, 1, t & 1);
    attn_step<<<Bz, 512, 0, stream>>>(gl_Wq, gl_bq, gl_V,
        pt_Wq, pt_bq, pt_V, t, (t+1) & 1, out);
  }
}